// Round 7
// baseline (417.645 us; speedup 1.0000x reference)
//
#include <hip/hip_runtime.h>
#include <stdint.h>

typedef short short8 __attribute__((ext_vector_type(8)));
typedef short short4v __attribute__((ext_vector_type(4)));
typedef float floatx4 __attribute__((ext_vector_type(4)));
typedef unsigned uint4v __attribute__((ext_vector_type(4)));

#define H_  8
#define NB_ 4      // batch N
#define S_  1024
#define D_  512
#define KD_ 64

__device__ __forceinline__ short f2bf(float f){
    unsigned u = __builtin_bit_cast(unsigned, f);
    u += 0x7fffu + ((u>>16)&1u);
    return (short)(u>>16);
}
__device__ __forceinline__ float wred_addf(float x){
    #pragma unroll
    for(int o=32;o>0;o>>=1) x += __shfl_xor(x,o,64);
    return x;
}
__device__ __forceinline__ float wred_maxf(float x){
    #pragma unroll
    for(int o=32;o>0;o>>=1) x = fmaxf(x,__shfl_xor(x,o,64));
    return x;
}
__device__ __forceinline__ unsigned umaxu(unsigned a, unsigned b){ return a>b?a:b; }
__device__ __forceinline__ unsigned uminu(unsigned a, unsigned b){ return a<b?a:b; }

// DPP-based wave64 reductions: pure VALU, result uniform via readlane.
template<int CTRL, int RMASK, int BC>
__device__ __forceinline__ unsigned dppu(unsigned x){
    return (unsigned)__builtin_amdgcn_update_dpp(0, (int)x, CTRL, RMASK, 0xf, BC);
}
template<int CTRL, int RMASK>
__device__ __forceinline__ unsigned dppu_m1(unsigned x){
    return (unsigned)__builtin_amdgcn_update_dpp((int)0xFFFFFFFF, (int)x, CTRL, RMASK, 0xf, 0);
}
__device__ __forceinline__ unsigned wsum_dpp_u(unsigned x){
    x += dppu<0x111,0xf,1>(x);
    x += dppu<0x112,0xf,1>(x);
    x += dppu<0x114,0xf,1>(x);
    x += dppu<0x118,0xf,1>(x);
    x += dppu<0x142,0xa,0>(x);
    x += dppu<0x143,0xc,0>(x);
    return (unsigned)__builtin_amdgcn_readlane((int)x, 63);
}
__device__ __forceinline__ unsigned wmax_dpp_u(unsigned x){
    x = umaxu(x, dppu<0x111,0xf,1>(x));
    x = umaxu(x, dppu<0x112,0xf,1>(x));
    x = umaxu(x, dppu<0x114,0xf,1>(x));
    x = umaxu(x, dppu<0x118,0xf,1>(x));
    x = umaxu(x, dppu<0x142,0xa,0>(x));
    x = umaxu(x, dppu<0x143,0xc,0>(x));
    return (unsigned)__builtin_amdgcn_readlane((int)x, 63);
}
__device__ __forceinline__ unsigned wmin_dpp_u(unsigned x){
    x = uminu(x, dppu_m1<0x111,0xf>(x));
    x = uminu(x, dppu_m1<0x112,0xf>(x));
    x = uminu(x, dppu_m1<0x114,0xf>(x));
    x = uminu(x, dppu_m1<0x118,0xf>(x));
    x = uminu(x, dppu_m1<0x142,0xa>(x));
    x = uminu(x, dppu_m1<0x143,0xc>(x));
    return (unsigned)__builtin_amdgcn_readlane((int)x, 63);
}
__device__ __forceinline__ float addu_f(float a, unsigned b){
    return a + __builtin_bit_cast(float, b);
}
__device__ __forceinline__ float wsum_dpp_f(float x){
    x = addu_f(x, dppu<0x111,0xf,1>(__builtin_bit_cast(unsigned,x)));
    x = addu_f(x, dppu<0x112,0xf,1>(__builtin_bit_cast(unsigned,x)));
    x = addu_f(x, dppu<0x114,0xf,1>(__builtin_bit_cast(unsigned,x)));
    x = addu_f(x, dppu<0x118,0xf,1>(__builtin_bit_cast(unsigned,x)));
    x = addu_f(x, dppu<0x142,0xa,0>(__builtin_bit_cast(unsigned,x)));
    x = addu_f(x, dppu<0x143,0xc,0>(__builtin_bit_cast(unsigned,x)));
    return __builtin_bit_cast(float, (unsigned)__builtin_amdgcn_readlane((int)__builtin_bit_cast(unsigned, x), 63));
}
__device__ __forceinline__ unsigned cvt_pk_bf16(float a, float b){
    unsigned r;
    asm("v_cvt_pk_bf16_f32 %0, %1, %2" : "=v"(r) : "v"(a), "v"(b));
    return r;
}
// hybrid top-k probe count: 8 elements on VALU (addc + DPP reduce),
// 8 elements on SALU (ballot + popcount).
__device__ __forceinline__ unsigned count128(const unsigned (&kv)[16], unsigned mid){
    unsigned cv = 0u;
    #pragma unroll
    for(int j=0;j<8;j++) cv += (unsigned)(kv[j] >= mid);
    unsigned cs = 0u;
    #pragma unroll
    for(int j=8;j<16;j++) cs += (unsigned)__popcll(__ballot(kv[j] >= mid));
    return wsum_dpp_u(cv) + cs;
}

// ---------------- merged prep: wtrans5 + wtrans4 + cvt2 + graph softmax ----------------
__global__ __launch_bounds__(256) void prep_kernel(
    const float* __restrict__ dWk, const float* __restrict__ dWv,
    const float* __restrict__ eWk, const float* __restrict__ eWv, const float* __restrict__ eWq,
    const float* __restrict__ dWo, const float* __restrict__ eWo,
    const float* __restrict__ W1, const float* __restrict__ W2,
    const float* __restrict__ y, const float* __restrict__ z,
    const float* __restrict__ g0, const float* __restrict__ g1,
    short* __restrict__ wKVd, short* __restrict__ wKVe, short* __restrict__ wQet,
    short* __restrict__ oWod, short* __restrict__ oWoe,
    short* __restrict__ oW1, short* __restrict__ oW2,
    short* __restrict__ y_bf, short* __restrict__ z_bf,
    short* __restrict__ og0, short* __restrict__ og1)
{
    __shared__ float t[32][33];
    int id = blockIdx.x;
    int tid = threadIdx.x;
    if(id < 1280){
        // wtrans5: per-head [512][64] -> [64][512] bf16
        int zz = id >> 5; int rem = id & 31; int by = rem >> 1, bx = rem & 1;
        int w = zz>>3, h = zz&7;
        const float* src; short* dst;
        if(w==0){ src = dWk + h*32768; dst = wKVd + h*65536; }
        else if(w==1){ src = dWv + h*32768; dst = wKVd + h*65536 + 32768; }
        else if(w==2){ src = eWk + h*32768; dst = wKVe + h*65536; }
        else if(w==3){ src = eWv + h*32768; dst = wKVe + h*65536 + 32768; }
        else { src = eWq + h*32768; dst = wQet + h*32768; }
        int c0 = bx*32, r0 = by*32;
        int r = tid>>3, cq = (tid&7)*4;
        #pragma unroll
        for(int i=0;i<4;i++) t[r][cq+i] = src[(r0+r)*64 + c0+cq+i];
        __syncthreads();
        int c = tid>>3, rq = (tid&7)*4;
        #pragma unroll
        for(int i=0;i<4;i++) dst[(c0+c)*512 + r0+rq+i] = f2bf(t[rq+i][c]);
    } else if(id < 3840){
        // wtrans4
        int id2 = id - 1280;
        const float* src; short* dst; int R, C, c0, r0;
        if(id2 < 512){
            src = (id2<256)? dWo : eWo; dst = (id2<256)? oWod : oWoe;
            int tt = id2 & 255; R = 512; C = 512;
            c0 = (tt&15)*32; r0 = (tt>>4)*32;
        } else if(id2 < 1536){
            src = W1; dst = oW1; int tt = id2 - 512; R = 512; C = 2048;
            c0 = (tt&63)*32; r0 = (tt>>6)*32;
        } else {
            src = W2; dst = oW2; int tt = id2 - 1536; R = 2048; C = 512;
            c0 = (tt&15)*32; r0 = (tt>>4)*32;
        }
        int r = tid>>3, cq = (tid&7)*4;
        #pragma unroll
        for(int i=0;i<4;i++) t[r][cq+i] = src[(long)(r0+r)*C + c0+cq+i];
        __syncthreads();
        int c = tid>>3, rq = (tid&7)*4;
        #pragma unroll
        for(int i=0;i<4;i++) dst[(long)(c0+c)*R + r0+rq+i] = f2bf(t[rq+i][c]);
    } else if(id < 7936){
        // cvt2: fp32 -> bf16 for y and z
        int tt = id - 3840;
        int bx = tt & 2047, by = tt >> 11;
        const float* in = by ? z : y;
        short* out = by ? z_bf : y_bf;
        int i = (bx*256 + tid)*4;
        floatx4 v = *(const floatx4*)(in + i);
        short4v r;
        #pragma unroll
        for(int j=0;j<4;j++) r[j] = f2bf(v[j]);
        *(short4v*)(out + i) = r;
    } else {
        // graph softmax -> 0.5*softmax bf16
        int tt = id - 7936;
        int row = tt & 1023, by = tt >> 10;
        const float* g = by ? g1 : g0;
        short* o = by ? og1 : og0;
        const float* gr = g + (long)row*S_;
        short* orow = o + (long)row*S_;
        int wave = tid>>6, lane = tid&63;
        float* red = &t[0][0];
        float v[4]; float mx = -3.0e38f;
        #pragma unroll
        for(int i=0;i<4;i++){ v[i] = gr[tid + 256*i]; mx = fmaxf(mx, v[i]); }
        mx = wred_maxf(mx);
        if(lane==0) red[wave] = mx;
        __syncthreads();
        mx = fmaxf(fmaxf(red[0],red[1]), fmaxf(red[2],red[3]));
        float s = 0.f;
        #pragma unroll
        for(int i=0;i<4;i++){ v[i] = __expf(v[i]-mx); s += v[i]; }
        s = wred_addf(s);
        if(lane==0) red[4+wave] = s;
        __syncthreads();
        s = red[4]+red[5]+red[6]+red[7];
        float inv = 0.5f/s;
        #pragma unroll
        for(int i=0;i<4;i++) orow[tid + 256*i] = f2bf(v[i]*inv);
    }
}

// ---------------- merged dec+enc KV projection ----------------
__global__ __launch_bounds__(256) void gemm_projkv_kernel(
    const short* __restrict__ Ay, const short* __restrict__ Az,
    const short* __restrict__ Bd, const short* __restrict__ Be,
    const float* __restrict__ dbk, const float* __restrict__ dbv,
    const float* __restrict__ ebk, const float* __restrict__ ebv,
    short* __restrict__ Kd, short* __restrict__ Vd,
    short* __restrict__ Ke, short* __restrict__ Ve)
{
    __shared__ short As[64*32];
    __shared__ short Bs[128*32];
    int z = blockIdx.z; int enc = z>>3; int zl = z&7;
    const short* A  = enc ? Az : Ay;
    const short* Bb = (enc ? Be : Bd) + zl*65536;
    const float* b1 = enc ? ebk : dbk;
    const float* b2 = enc ? ebv : dbv;
    short* o1 = enc ? Ke : Kd;
    short* o2 = enc ? Ve : Vd;
    int m0 = blockIdx.x*64;
    int tid = threadIdx.x, wave = tid>>6, lane = tid&63, quad = lane>>4, nl = lane&15;
    int wm = (wave&1)*32, wn = (wave>>1)*64;
    floatx4 acc[2][4];
    #pragma unroll
    for(int i=0;i<2;i++)
        #pragma unroll
        for(int j=0;j<4;j++) acc[i][j] = (floatx4){0.f,0.f,0.f,0.f};
    int r = tid>>2, c = (tid&3)*8;
    for(int k0=0;k0<512;k0+=32){
        __syncthreads();
        __builtin_amdgcn_global_load_lds(
            (const __attribute__((address_space(1))) unsigned*)(A + (long)(m0 + r)*512 + k0 + c),
            (__attribute__((address_space(3))) unsigned*)((char*)As + wave*1024), 16, 0, 0);
        #pragma unroll
        for(int i=0;i<2;i++)
            __builtin_amdgcn_global_load_lds(
                (const __attribute__((address_space(1))) unsigned*)(Bb + (long)(r + i*64)*512 + k0 + c),
                (__attribute__((address_space(3))) unsigned*)((char*)Bs + i*4096 + wave*1024), 16, 0, 0);
        __syncthreads();
        short8 af[2], bfr[4];
        #pragma unroll
        for(int i=0;i<2;i++) af[i] = *(const short8*)(As + (wm + i*16 + nl)*32 + quad*8);
        #pragma unroll
        for(int j=0;j<4;j++) bfr[j] = *(const short8*)(Bs + (wn + j*16 + nl)*32 + quad*8);
        #pragma unroll
        for(int i=0;i<2;i++)
            #pragma unroll
            for(int j=0;j<4;j++)
                acc[i][j] = __builtin_amdgcn_mfma_f32_16x16x32_bf16(af[i],bfr[j],acc[i][j],0,0,0);
    }
    #pragma unroll
    for(int j=0;j<4;j++){
        int n = wn + j*16 + nl;
        float bv = (n >= 64) ? b2[zl*64 + n - 64] : b1[zl*64 + n];
        #pragma unroll
        for(int i=0;i<2;i++){
            #pragma unroll
            for(int rr=0;rr<4;rr++){
                int m = m0 + wm + i*16 + quad*4 + rr;
                float v = acc[i][j][rr] + bv;
                long zb = (long)(zl*NB_ + (m>>10));
                if(n >= 64) o2[ (zb*KD_ + (n-64))*S_ + (m&1023) ] = f2bf(v);
                else        o1[ (zb*S_ + (m&1023))*KD_ + n ] = f2bf(v);
            }
        }
    }
}

// ---------------- projection GEMM for Q (single) ----------------
__global__ __launch_bounds__(256) void gemm_projq_kernel(
    const short* __restrict__ A, const short* __restrict__ Bt,
    const float* __restrict__ b1, short* __restrict__ o1)
{
    __shared__ short As[64*32];
    __shared__ short Bs[64*32];
    int z = blockIdx.z;
    int m0 = blockIdx.x*64;
    const short* Bb = Bt + (long)z*(64*512);
    int tid = threadIdx.x, wave = tid>>6, lane = tid&63, quad = lane>>4, nl = lane&15;
    int wm = (wave&1)*32, wn = (wave>>1)*32;
    floatx4 acc[2][2];
    #pragma unroll
    for(int i=0;i<2;i++)
        #pragma unroll
        for(int j=0;j<2;j++) acc[i][j] = (floatx4){0.f,0.f,0.f,0.f};
    int r = tid>>2, c = (tid&3)*8;
    for(int k0=0;k0<512;k0+=32){
        __syncthreads();
        __builtin_amdgcn_global_load_lds(
            (const __attribute__((address_space(1))) unsigned*)(A + (long)(m0 + r)*512 + k0 + c),
            (__attribute__((address_space(3))) unsigned*)((char*)As + wave*1024), 16, 0, 0);
        __builtin_amdgcn_global_load_lds(
            (const __attribute__((address_space(1))) unsigned*)(Bb + (long)r*512 + k0 + c),
            (__attribute__((address_space(3))) unsigned*)((char*)Bs + wave*1024), 16, 0, 0);
        __syncthreads();
        short8 af[2], bfr[2];
        #pragma unroll
        for(int i=0;i<2;i++) af[i] = *(const short8*)(As + (wm + i*16 + nl)*32 + quad*8);
        #pragma unroll
        for(int j=0;j<2;j++) bfr[j] = *(const short8*)(Bs + (wn + j*16 + nl)*32 + quad*8);
        #pragma unroll
        for(int i=0;i<2;i++)
            #pragma unroll
            for(int j=0;j<2;j++)
                acc[i][j] = __builtin_amdgcn_mfma_f32_16x16x32_bf16(af[i],bfr[j],acc[i][j],0,0,0);
    }
    #pragma unroll
    for(int j=0;j<2;j++){
        int n = wn + j*16 + nl;
        float bv = b1[z*64 + n];
        #pragma unroll
        for(int i=0;i<2;i++){
            #pragma unroll
            for(int rr=0;rr<4;rr++){
                int m = m0 + wm + i*16 + quad*4 + rr;
                float v = acc[i][j][rr] + bv;
                long zb = (long)(z*NB_ + (m>>10));
                o1[ (zb*S_ + (m&1023))*KD_ + n ] = f2bf(v);
            }
        }
    }
}

// ---------------- big MFMA GEMM, m97 pattern (MLP1) ----------------
template<int TM, int TN, int OUTBF, int RELU>
__global__ __launch_bounds__(256) void gemm_big_kernel(
    const short* __restrict__ A, const short* __restrict__ Bt, const float* __restrict__ bias,
    void* __restrict__ out, int M, int N, int K)
{
    __shared__ short As[TM*32];
    __shared__ short Bs[TN*32];
    int m0 = blockIdx.x*TM, n0 = blockIdx.y*TN;
    int tid = threadIdx.x, wave = tid>>6, lane = tid&63, quad = lane>>4, nl = lane&15;
    constexpr int MI = TM/32, NI = TN/32;
    int wm = (wave&1)*(TM/2), wn = (wave>>1)*(TN/2);
    floatx4 acc[MI][NI];
    #pragma unroll
    for(int i=0;i<MI;i++)
        #pragma unroll
        for(int j=0;j<NI;j++) acc[i][j] = (floatx4){0.f,0.f,0.f,0.f};

    int r = tid>>2, c = (tid&3)*8;
    for(int k0=0;k0<K;k0+=32){
        __syncthreads();
        #pragma unroll
        for(int i=0;i<TM/64;i++)
            __builtin_amdgcn_global_load_lds(
                (const __attribute__((address_space(1))) unsigned*)(A + (long)(m0 + r + i*64)*K + k0 + c),
                (__attribute__((address_space(3))) unsigned*)((char*)As + i*4096 + wave*1024),
                16, 0, 0);
        #pragma unroll
        for(int i=0;i<TN/64;i++)
            __builtin_amdgcn_global_load_lds(
                (const __attribute__((address_space(1))) unsigned*)(Bt + (long)(n0 + r + i*64)*K + k0 + c),
                (__attribute__((address_space(3))) unsigned*)((char*)Bs + i*4096 + wave*1024),
                16, 0, 0);
        __syncthreads();
        short8 af[MI], bfr[NI];
        #pragma unroll
        for(int i=0;i<MI;i++) af[i] = *(const short8*)(As + (wm + i*16 + nl)*32 + quad*8);
        #pragma unroll
        for(int j=0;j<NI;j++) bfr[j] = *(const short8*)(Bs + (wn + j*16 + nl)*32 + quad*8);
        #pragma unroll
        for(int i=0;i<MI;i++)
            #pragma unroll
            for(int j=0;j<NI;j++)
                acc[i][j] = __builtin_amdgcn_mfma_f32_16x16x32_bf16(af[i],bfr[j],acc[i][j],0,0,0);
    }
    #pragma unroll
    for(int j=0;j<NI;j++){
        int n = n0 + wn + j*16 + nl;
        float bv = bias[n];
        #pragma unroll
        for(int i=0;i<MI;i++){
            #pragma unroll
            for(int rr=0;rr<4;rr++){
                int m = m0 + wm + i*16 + quad*4 + rr;
                float v = acc[i][j][rr] + bv;
                if(RELU) v = fmaxf(v, 0.f);
                if(OUTBF) ((short*)out)[(long)m*N + n] = f2bf(v);
                else      ((float*)out)[(long)m*N + n] = v;
            }
        }
    }
}

// ---------------- fused GEMM + residual + LayerNorm ----------------
// out[m] = LN(A[m]@B^T + bias + res[m]). N fixed at 512 (full row per block).
// TM=16 rows/block, 1024 threads (16 waves, 32 cols each), grid M/16 = 256.
template<int OUTB>
__global__ __launch_bounds__(1024) void gemm_ln_kernel(
    const short* __restrict__ A, const short* __restrict__ Bt,
    const float* __restrict__ bias, const float* __restrict__ res,
    float* __restrict__ outf, short* __restrict__ outb, int K)
{
    __shared__ short As[16*32];       // 1 KiB
    __shared__ short Bs[512*32];      // 32 KiB
    __shared__ float redn[2][16][16]; // 2 KiB
    int m0 = blockIdx.x*16;
    int tid = threadIdx.x, wave = tid>>6, lane = tid&63, quad = lane>>4, nl = lane&15;
    int wn = wave*32;
    floatx4 acc[2];
    acc[0] = (floatx4){0.f,0.f,0.f,0.f};
    acc[1] = (floatx4){0.f,0.f,0.f,0.f};
    int r = tid>>2, c = (tid&3)*8;    // r in 0..255
    for(int k0=0;k0<K;k0+=32){
        __syncthreads();
        if(wave==0)
            __builtin_amdgcn_global_load_lds(
                (const __attribute__((address_space(1))) unsigned*)(A + (long)(m0 + (lane>>2))*K + k0 + (lane&3)*8),
                (__attribute__((address_space(3))) unsigned*)((char*)As), 16, 0, 0);
        #pragma unroll
        for(int i=0;i<2;i++)
            __builtin_amdgcn_global_load_lds(
                (const __attribute__((address_space(1))) unsigned*)(Bt + (long)(r + i*256)*K + k0 + c),
                (__attribute__((address_space(3))) unsigned*)((char*)Bs + i*16384 + wave*1024), 16, 0, 0);
        __syncthreads();
        short8 af = *(const short8*)(As + nl*32 + quad*8);
        short8 b0 = *(const short8*)(Bs + (wn + nl)*32 + quad*8);
        short8 b1 = *(const short8*)(Bs + (wn + 16 + nl)*32 + quad*8);
        acc[0] = __builtin_amdgcn_mfma_f32_16x16x32_bf16(af,b0,acc[0],0,0,0);
        acc[1] = __builtin_amdgcn_mfma_f32_16x16x32_bf16(af,b1,acc[1],0,0,0);
    }
    // epilogue: t = acc + bias + res
    float t[2][4];
    #pragma unroll
    for(int j=0;j<2;j++){
        int n = wn + j*16 + nl;
        float bv = bias[n];
        #pragma unroll
        for(int rr=0;rr<4;rr++){
            int m = quad*4 + rr;
            t[j][rr] = acc[j][rr] + bv + res[(long)(m0+m)*512 + n];
        }
    }
    // per-quad (16-lane) reduce over nl for each rr: sums over this wave's 32 cols
    #pragma unroll
    for(int rr=0;rr<4;rr++){
        float s  = t[0][rr] + t[1][rr];
        float s2 = t[0][rr]*t[0][rr] + t[1][rr]*t[1][rr];
        #pragma unroll
        for(int o=1;o<16;o<<=1){ s += __shfl_xor(s,o,16); s2 += __shfl_xor(s2,o,16); }
        if(nl==0){
            redn[0][quad*4+rr][wave] = s;
            redn[1][quad*4+rr][wave] = s2;
        }
    }
    __syncthreads();
    #pragma unroll
    for(int rr=0;rr<4;rr++){
        int row = quad*4 + rr;
        float s = 0.f, s2 = 0.f;
        #pragma unroll
        for(int b=0;b<4;b++){
            floatx4 p  = *(const floatx4*)&redn[0][row][b*4];
            floatx4 p2 = *(const floatx4*)&redn[1][row][b*4];
            s  += p[0]+p[1]+p[2]+p[3];
            s2 += p2[0]+p2[1]+p2[2]+p2[3];
        }
        float mean = s*(1.f/512.f);
        float var = s2*(1.f/512.f) - mean*mean;
        float rs = rsqrtf(var + 1e-5f);
        #pragma unroll
        for(int j=0;j<2;j++){
            int n = wn + j*16 + nl;
            float o = (t[j][rr] - mean)*rs;
            outf[(long)(m0+row)*512 + n] = o;
            if(OUTB) outb[(long)(m0+row)*512 + n] = f2bf(o);
        }
    }
}

// ---------------- fused attention v13 ----------------
// r6 skeleton + interpolation (secant) search: track (lo,clo),(hi,chi) and
// alternate interpolation / bisection steps -> ~4-5 probes vs ~9-10.
__global__ __launch_bounds__(512,6) void attn_kernel(
    const short* __restrict__ Qb, const short* __restrict__ Kb, const short* __restrict__ Vt,
    const short* __restrict__ graph, short* __restrict__ ctx, int causal)
{
    __shared__ short attb[16*1024];   // 32 KiB
    __shared__ float pbuf[16*68];     // 4.25 KiB
    int hn = blockIdx.x, qt = blockIdx.y;
    int h = hn>>2, n = hn&3;
    int q0 = qt*16;
    int tid=threadIdx.x, wave=tid>>6, lane=tid&63, quad=lane>>4, nl=lane&15;

    if(causal){
        uint4v fv = (uint4v){0xff80ff80u,0xff80ff80u,0xff80ff80u,0xff80ff80u};
        #pragma unroll
        for(int i=0;i<4;i++) *(uint4v*)((char*)attb + tid*16 + i*8192) = fv;
        __syncthreads();
    }

    // ---- phase 1: scores -> bf16 LDS (rot 8q), diagonal tile masked to -inf ----
    const short* Qp = Qb + ((long)hn*S_ + q0 + nl)*KD_ + quad*8;
    short8 aq0 = *(const short8*)(Qp);
    short8 aq1 = *(const short8*)(Qp + 32);
    const short* Kp = Kb + (long)hn*S_*KD_;
    int stmax = causal ? qt : 63;
    for(int st=wave; st<=stmax; st+=8){
        const short* kp = Kp + (st*16 + nl)*KD_ + quad*8;
        short8 b0 = *(const short8*)(kp);
        short8 b1 = *(const short8*)(kp + 32);
        floatx4 cc = (floatx4){0.f,0.f,0.f,0.f};
        cc = __builtin_amdgcn_mfma_f32_16x16x32_bf16(aq0,b0,cc,0,0,0);
        cc = __builtin_amdgcn_mfma_f32_16x16x32_bf16(aq1,b1,cc,0,0,0);
        int s = st*16 + nl;
        #pragma unroll
        for(int rr=0;rr<4;rr++){
            int q = quad*4 + rr;
            short val = f2bf(cc[rr]*0.125f);
            if(causal && s > q0 + q) val = (short)0xff80;   // -inf
            attb[q*1024 + ((s + 8*q)&1023)] = val;
        }
    }
    __syncthreads();

    // ---- phase 2: top-128 + softmax + graph blend; 2 sequential rows/wave ----
    #pragma unroll 1
    for(int rp=0; rp<2; ++rp){
        int q = wave*2 + rp;
        int qg = q0 + q;
        short* rowp = attb + q*1024;
        int sb = lane*16;
        int p0 = (sb + 8*q) & 1023;
        const short* grow = graph + (long)qg*1024 + sb;
        uint4v g0 = *(const uint4v*)(grow);
        uint4v g1 = *(const uint4v*)(grow + 8);
        uint4v u0 = *(const uint4v*)(rowp + p0);
        uint4v u1 = *(const uint4v*)(rowp + ((p0+8)&1023));
        unsigned pr[8];
        #pragma unroll
        for(int i=0;i<4;i++){ pr[i] = u0[i]; pr[4+i] = u1[i]; }
        unsigned kv[16];
        #pragma unroll
        for(int i=0;i<8;i++){
            unsigned u = pr[i];
            unsigned kp = u ^ (0x80008000u + ((u>>15)&0x00010001u)*0x7fffu);
            kv[2*i]   = kp & 0xffffu;
            kv[2*i+1] = kp >> 16;
        }
        unsigned a0 = umaxu(kv[0],kv[1]),  a1 = umaxu(kv[2],kv[3]);
        unsigned a2 = umaxu(kv[4],kv[5]),  a3 = umaxu(kv[6],kv[7]);
        unsigned a4 = umaxu(kv[8],kv[9]),  a5 = umaxu(kv[10],kv[11]);
        unsigned a6 = umaxu(kv[12],kv[13]),a7 = umaxu(kv[14],kv[15]);
        unsigned mk = umaxu(umaxu(umaxu(a0,a1),umaxu(a2,a3)), umaxu(umaxu(a4,a5),umaxu(a6,a7)));
        unsigned mks = wmax_dpp_u(mk);
        unsigned lmin = wmin_dpp_u(mk);
        // bracket probe at lmin
        unsigned lo, hi, clo, chi;
        {
            unsigned cnt = count128(kv, lmin);
            if(cnt >= 128u){
                lo = lmin; clo = cnt;
                hi = (cnt == 128u) ? (lmin + 1u) : (mks + 1u); chi = 0u;
            } else {
                lo = 0u; clo = 1024u; hi = lmin; chi = cnt;
            }
        }
        // alternating interpolation / bisection
        int it = 0;
        while(hi - lo > 1u){
            unsigned span = hi - lo;
            unsigned mid;
            if((it++ & 1) == 0){
                float fr = (float)(clo - 128u) / (float)(clo - chi);
                unsigned off = (unsigned)(fr * (float)span);
                off = off < 1u ? 1u : off;
                off = off > span - 1u ? span - 1u : off;
                mid = lo + off;
            } else {
                mid = lo + (span >> 1);
            }
            unsigned cnt = count128(kv, mid);
            if(cnt >= 128u){ lo = mid; clo = cnt; if(cnt == 128u) break; }
            else { hi = mid; chi = cnt; }
        }
        // row max as float (uniform)
        unsigned uo = (mks & 0x8000u) ? ((mks & 0x7fffu)<<16) : ((~mks)<<16);
        float mxf = __builtin_bit_cast(float, uo);
        float ev[16]; float sm = 0.f;
        #pragma unroll
        for(int i=0;i<8;i++){
            float f0 = __builtin_bit_cast(float, pr[i] << 16);
            float f1 = __builtin_bit_cast(float, pr[i] & 0xffff0000u);
            float e0 = __expf(f0 - mxf);
            float e1 = __expf(f1 - mxf);
            e0 = (kv[2*i]   >= lo) ? e0 : 0.f;
            e1 = (kv[2*i+1] >= lo) ? e1 : 0.f;
            ev[2*i] = e0; ev[2*i+1] = e1;
            sm += e0 + e1;
        }
        sm = wsum_dpp_f(sm);
        float inv = 0.5f / sm;
        uint4v w0, w1;
        #pragma unroll
        for(int i=0;i<4;i++){
            float gl0 = __builtin_bit_cast(float, g0[i] << 16);
            float gh0 = __builtin_bit_cast(float, g0[i] & 0xffff0000u);
            w0[i] = cvt_pk_bf16(fmaf(ev[2*i], inv, gl0), fmaf(ev[2*i+1], inv, gh0));
            float gl1 = __builtin_bit_cast(float, g1[i] << 16);
            float gh1 = __builtin_bit_cast(float, g1[i] & 0xffff0000u);
            w1[i] = cvt_pk_bf16(fmaf(ev[8+2*i], inv, gl1), fmaf(ev[8+2*i+1], inv, gh1));
        }
        *(uint4v*)(rowp + p0) = w0;
        *(uint4v*)(rowp + ((p0+8)&1023)) = w1;
    }
    __syncthreads();

    // ---- phase 3: ctx = att @ V, split over s-halves (sh), v-quarters (vh) ----
    int vh = wave & 3, sh = wave >> 2;
    int v0 = vh*16;
    const short* Vp = Vt + ((long)hn*KD_ + v0 + nl)*S_;
    floatx4 o4 = (floatx4){0.f,0.f,0.f,0.f};
    int arow = nl;
    int sbase = sh*512;
    for(int s0=sbase; s0<sbase+512; s0+=32){
        int cs = (s0 + quad*8 + 8*arow) & 1023;
        short8 ap = *(const short8*)(attb + arow*1024 + cs);
        short8 bv = *(const short8*)(Vp + s0 + quad*8);
        o4 = __builtin_amdgcn_mfma_f32_16x16x32_bf16(ap,bv,o4,0,0,0);
    }
    if(sh==1){
        #pragma unroll
        for(int rr=0;rr<4;rr++) pbuf[(quad*4+rr)*68 + v0 + nl] = o4[rr];
    }
    __syncthreads();
    if(sh==0){
        #pragma unroll
        for(int rr=0;rr<4;rr++){
            int q = quad*4 + rr;
            float v = o4[rr] + pbuf[q*68 + v0 + nl];
            ctx[ ((long)(n*S_ + q0 + q))*512 + h*KD_ + v0 + nl ] = f2bf(v);
        }
    }
}

extern "C" void kernel_launch(void* const* d_in, const int* in_sizes, int n_in,
                              void* d_out, int out_size, void* d_ws, size_t ws_size,
                              hipStream_t stream)
{
    const float* z         = (const float*)d_in[0];
    const float* y         = (const float*)d_in[1];
    const float* graph_dec = (const float*)d_in[2];
    const float* graph_enc = (const float*)d_in[3];
    const float* dec_Wk = (const float*)d_in[4];  const float* dec_bk = (const float*)d_in[5];
    const float* dec_Wv = (const float*)d_in[6];  const float* dec_bv = (const float*)d_in[7];
    const float* dec_Wo = (const float*)d_in[8];  const float* dec_bo = (const float*)d_in[9];
    const float* enc_Wk = (const float*)d_in[10]; const float* enc_bk = (const float*)d_in[11];
    const float* enc_Wq = (const float*)d_in[12]; const float* enc_bq = (const float*)d_in[13];
    const float* enc_Wv = (const float*)d_in[14]; const float* enc_bv = (const float*)d_in[15];
    const float* enc_Wo = (const float*)d_in[16]; const float* enc_bo = (const float*)d_in[17];
    const float* fc_W1  = (const float*)d_in[18]; const float* fc_b1  = (const float*)d_in[19];
    const float* fc_W2  = (const float*)d_in[20]; const float* fc_b2  = (const float*)d_in[21];

    char* ws = (char*)d_ws;
    short* gdec  = (short*)(ws + 0x0000000);
    short* genc  = (short*)(ws + 0x0400000);
    short* y_bf  = (short*)(ws + 0x0800000);
    short* z_bf  = (short*)(ws + 0x0C00000);
    short* Kdec  = (short*)(ws + 0x1000000);
    short* Vtdec = (short*)(ws + 0x1400000);
    short* Kenc  = (short*)(ws + 0x1800000);
    short* Vtenc = (short*)(ws + 0x1C00000);
    short* Qenc  = (short*)(ws + 0x2000000);
    short* ctx   = (short*)(ws + 0x2400000);
    float* hbuf  = (float*)(ws + 0x3000000);
    short* h_bf  = (short*)(ws + 0x3800000);
    float* h2    = (float*)(ws + 0x3C00000);
    short* h2_bf = (short*)(ws + 0x4400000);
    short* fc1   = (short*)(ws + 0x4800000);
    short* wKVd  = (short*)(ws + 0x5800000);
    short* wKVe  = (short*)(ws + 0x5900000);
    short* wQet  = (short*)(ws + 0x5A00000);
    short* wOdt  = (short*)(ws + 0x5A80000);
    short* wOet  = (short*)(ws + 0x5B00000);
    short* wF1t  = (short*)(ws + 0x5B80000);
    short* wF2t  = (short*)(ws + 0x5D80000);
    float* outp  = (float*)d_out;

    // 1) all preprocessing in one dispatch
    prep_kernel<<<dim3(9984),dim3(256),0,stream>>>(
        dec_Wk, dec_Wv, enc_Wk, enc_Wv, enc_Wq, dec_Wo, enc_Wo, fc_W1, fc_W2,
        y, z, graph_dec, graph_enc,
        wKVd, wKVe, wQet, wOdt, wOet, wF1t, wF2t, y_bf, z_bf, gdec, genc);
    // 2) dec + enc KV projections in one dispatch
    gemm_projkv_kernel<<<dim3(64,1,16),dim3(256),0,stream>>>(
        y_bf, z_bf, wKVd, wKVe, dec_bk, dec_bv, enc_bk, enc_bv,
        Kdec, Vtdec, Kenc, Vtenc);
    // 3) decoder attention
    attn_kernel<<<dim3(32,64),dim3(512),0,stream>>>(Kdec, Kdec, Vtdec, gdec, ctx, 1);
    // 4) Wo + residual + LN fused
    gemm_ln_kernel<1><<<dim3(256),dim3(1024),0,stream>>>(ctx, wOdt, dec_bo, y, hbuf, h_bf, 512);
    // 5) query projection
    gemm_projq_kernel<<<dim3(64,1,8),dim3(256),0,stream>>>(h_bf, wQet, enc_bq, Qenc);
    // 6) encoder-decoder attention
    attn_kernel<<<dim3(32,64),dim3(512),0,stream>>>(Qenc, Kenc, Vtenc, genc, ctx, 0);
    // 7) Wo + residual + LN fused
    gemm_ln_kernel<1><<<dim3(256),dim3(1024),0,stream>>>(ctx, wOet, enc_bo, hbuf, h2, h2_bf, 512);
    // 8) MLP layer 1 (relu, bf16 out)
    gemm_big_kernel<128,128,1,1><<<dim3(32,16),dim3(256),0,stream>>>(h2_bf, wF1t, fc_b1, fc1, 4096, 2048, 512);
    // 9) MLP layer 2 + residual + LN fused -> final output
    gemm_ln_kernel<0><<<dim3(256),dim3(1024),0,stream>>>(fc1, wF2t, fc_b2, h2, outp, (short*)0, 2048);
}

// Round 8
// 376.316 us; speedup vs baseline: 1.1098x; 1.1098x over previous
//
#include <hip/hip_runtime.h>
#include <stdint.h>

typedef short short8 __attribute__((ext_vector_type(8)));
typedef short short4v __attribute__((ext_vector_type(4)));
typedef float floatx4 __attribute__((ext_vector_type(4)));
typedef unsigned uint4v __attribute__((ext_vector_type(4)));

#define H_  8
#define NB_ 4      // batch N
#define S_  1024
#define D_  512
#define KD_ 64

__device__ __forceinline__ short f2bf(float f){
    unsigned u = __builtin_bit_cast(unsigned, f);
    u += 0x7fffu + ((u>>16)&1u);
    return (short)(u>>16);
}
__device__ __forceinline__ float wred_addf(float x){
    #pragma unroll
    for(int o=32;o>0;o>>=1) x += __shfl_xor(x,o,64);
    return x;
}
__device__ __forceinline__ float wred_maxf(float x){
    #pragma unroll
    for(int o=32;o>0;o>>=1) x = fmaxf(x,__shfl_xor(x,o,64));
    return x;
}
__device__ __forceinline__ unsigned umaxu(unsigned a, unsigned b){ return a>b?a:b; }
__device__ __forceinline__ unsigned uminu(unsigned a, unsigned b){ return a<b?a:b; }

// DPP-based wave64 reductions: pure VALU, result uniform via readlane.
template<int CTRL, int RMASK, int BC>
__device__ __forceinline__ unsigned dppu(unsigned x){
    return (unsigned)__builtin_amdgcn_update_dpp(0, (int)x, CTRL, RMASK, 0xf, BC);
}
template<int CTRL, int RMASK>
__device__ __forceinline__ unsigned dppu_m1(unsigned x){
    return (unsigned)__builtin_amdgcn_update_dpp((int)0xFFFFFFFF, (int)x, CTRL, RMASK, 0xf, 0);
}
__device__ __forceinline__ unsigned wsum_dpp_u(unsigned x){
    x += dppu<0x111,0xf,1>(x);
    x += dppu<0x112,0xf,1>(x);
    x += dppu<0x114,0xf,1>(x);
    x += dppu<0x118,0xf,1>(x);
    x += dppu<0x142,0xa,0>(x);
    x += dppu<0x143,0xc,0>(x);
    return (unsigned)__builtin_amdgcn_readlane((int)x, 63);
}
__device__ __forceinline__ unsigned wmax_dpp_u(unsigned x){
    x = umaxu(x, dppu<0x111,0xf,1>(x));
    x = umaxu(x, dppu<0x112,0xf,1>(x));
    x = umaxu(x, dppu<0x114,0xf,1>(x));
    x = umaxu(x, dppu<0x118,0xf,1>(x));
    x = umaxu(x, dppu<0x142,0xa,0>(x));
    x = umaxu(x, dppu<0x143,0xc,0>(x));
    return (unsigned)__builtin_amdgcn_readlane((int)x, 63);
}
__device__ __forceinline__ unsigned wmin_dpp_u(unsigned x){
    x = uminu(x, dppu_m1<0x111,0xf>(x));
    x = uminu(x, dppu_m1<0x112,0xf>(x));
    x = uminu(x, dppu_m1<0x114,0xf>(x));
    x = uminu(x, dppu_m1<0x118,0xf>(x));
    x = uminu(x, dppu_m1<0x142,0xa>(x));
    x = uminu(x, dppu_m1<0x143,0xc>(x));
    return (unsigned)__builtin_amdgcn_readlane((int)x, 63);
}
__device__ __forceinline__ float addu_f(float a, unsigned b){
    return a + __builtin_bit_cast(float, b);
}
__device__ __forceinline__ float wsum_dpp_f(float x){
    x = addu_f(x, dppu<0x111,0xf,1>(__builtin_bit_cast(unsigned,x)));
    x = addu_f(x, dppu<0x112,0xf,1>(__builtin_bit_cast(unsigned,x)));
    x = addu_f(x, dppu<0x114,0xf,1>(__builtin_bit_cast(unsigned,x)));
    x = addu_f(x, dppu<0x118,0xf,1>(__builtin_bit_cast(unsigned,x)));
    x = addu_f(x, dppu<0x142,0xa,0>(__builtin_bit_cast(unsigned,x)));
    x = addu_f(x, dppu<0x143,0xc,0>(__builtin_bit_cast(unsigned,x)));
    return __builtin_bit_cast(float, (unsigned)__builtin_amdgcn_readlane((int)__builtin_bit_cast(unsigned, x), 63));
}
__device__ __forceinline__ unsigned cvt_pk_bf16(float a, float b){
    unsigned r;
    asm("v_cvt_pk_bf16_f32 %0, %1, %2" : "=v"(r) : "v"(a), "v"(b));
    return r;
}
// hybrid top-k probe count: 8 elements on VALU (addc + DPP reduce),
// 8 elements on SALU (ballot + popcount).
__device__ __forceinline__ unsigned count128(const unsigned (&kv)[16], unsigned mid){
    unsigned cv = 0u;
    #pragma unroll
    for(int j=0;j<8;j++) cv += (unsigned)(kv[j] >= mid);
    unsigned cs = 0u;
    #pragma unroll
    for(int j=8;j<16;j++) cs += (unsigned)__popcll(__ballot(kv[j] >= mid));
    return wsum_dpp_u(cv) + cs;
}

// ---------------- merged prep: wtrans5 + wtrans4 + cvt2 + graph softmax ----------------
__global__ __launch_bounds__(256) void prep_kernel(
    const float* __restrict__ dWk, const float* __restrict__ dWv,
    const float* __restrict__ eWk, const float* __restrict__ eWv, const float* __restrict__ eWq,
    const float* __restrict__ dWo, const float* __restrict__ eWo,
    const float* __restrict__ W1, const float* __restrict__ W2,
    const float* __restrict__ y, const float* __restrict__ z,
    const float* __restrict__ g0, const float* __restrict__ g1,
    short* __restrict__ wKVd, short* __restrict__ wKVe, short* __restrict__ wQet,
    short* __restrict__ oWod, short* __restrict__ oWoe,
    short* __restrict__ oW1, short* __restrict__ oW2,
    short* __restrict__ y_bf, short* __restrict__ z_bf,
    short* __restrict__ og0, short* __restrict__ og1)
{
    __shared__ float t[32][33];
    int id = blockIdx.x;
    int tid = threadIdx.x;
    if(id < 1280){
        // wtrans5: per-head [512][64] -> [64][512] bf16
        int zz = id >> 5; int rem = id & 31; int by = rem >> 1, bx = rem & 1;
        int w = zz>>3, h = zz&7;
        const float* src; short* dst;
        if(w==0){ src = dWk + h*32768; dst = wKVd + h*65536; }
        else if(w==1){ src = dWv + h*32768; dst = wKVd + h*65536 + 32768; }
        else if(w==2){ src = eWk + h*32768; dst = wKVe + h*65536; }
        else if(w==3){ src = eWv + h*32768; dst = wKVe + h*65536 + 32768; }
        else { src = eWq + h*32768; dst = wQet + h*32768; }
        int c0 = bx*32, r0 = by*32;
        int r = tid>>3, cq = (tid&7)*4;
        #pragma unroll
        for(int i=0;i<4;i++) t[r][cq+i] = src[(r0+r)*64 + c0+cq+i];
        __syncthreads();
        int c = tid>>3, rq = (tid&7)*4;
        #pragma unroll
        for(int i=0;i<4;i++) dst[(c0+c)*512 + r0+rq+i] = f2bf(t[rq+i][c]);
    } else if(id < 3840){
        // wtrans4
        int id2 = id - 1280;
        const float* src; short* dst; int R, C, c0, r0;
        if(id2 < 512){
            src = (id2<256)? dWo : eWo; dst = (id2<256)? oWod : oWoe;
            int tt = id2 & 255; R = 512; C = 512;
            c0 = (tt&15)*32; r0 = (tt>>4)*32;
        } else if(id2 < 1536){
            src = W1; dst = oW1; int tt = id2 - 512; R = 512; C = 2048;
            c0 = (tt&63)*32; r0 = (tt>>6)*32;
        } else {
            src = W2; dst = oW2; int tt = id2 - 1536; R = 2048; C = 512;
            c0 = (tt&15)*32; r0 = (tt>>4)*32;
        }
        int r = tid>>3, cq = (tid&7)*4;
        #pragma unroll
        for(int i=0;i<4;i++) t[r][cq+i] = src[(long)(r0+r)*C + c0+cq+i];
        __syncthreads();
        int c = tid>>3, rq = (tid&7)*4;
        #pragma unroll
        for(int i=0;i<4;i++) dst[(long)(c0+c)*R + r0+rq+i] = f2bf(t[rq+i][c]);
    } else if(id < 7936){
        // cvt2: fp32 -> bf16 for y and z
        int tt = id - 3840;
        int bx = tt & 2047, by = tt >> 11;
        const float* in = by ? z : y;
        short* out = by ? z_bf : y_bf;
        int i = (bx*256 + tid)*4;
        floatx4 v = *(const floatx4*)(in + i);
        short4v r;
        #pragma unroll
        for(int j=0;j<4;j++) r[j] = f2bf(v[j]);
        *(short4v*)(out + i) = r;
    } else {
        // graph softmax -> 0.5*softmax bf16
        int tt = id - 7936;
        int row = tt & 1023, by = tt >> 10;
        const float* g = by ? g1 : g0;
        short* o = by ? og1 : og0;
        const float* gr = g + (long)row*S_;
        short* orow = o + (long)row*S_;
        int wave = tid>>6, lane = tid&63;
        float* red = &t[0][0];
        float v[4]; float mx = -3.0e38f;
        #pragma unroll
        for(int i=0;i<4;i++){ v[i] = gr[tid + 256*i]; mx = fmaxf(mx, v[i]); }
        mx = wred_maxf(mx);
        if(lane==0) red[wave] = mx;
        __syncthreads();
        mx = fmaxf(fmaxf(red[0],red[1]), fmaxf(red[2],red[3]));
        float s = 0.f;
        #pragma unroll
        for(int i=0;i<4;i++){ v[i] = __expf(v[i]-mx); s += v[i]; }
        s = wred_addf(s);
        if(lane==0) red[4+wave] = s;
        __syncthreads();
        s = red[4]+red[5]+red[6]+red[7];
        float inv = 0.5f/s;
        #pragma unroll
        for(int i=0;i<4;i++) orow[tid + 256*i] = f2bf(v[i]*inv);
    }
}

// ---------------- merged dec+enc KV projection ----------------
__global__ __launch_bounds__(256) void gemm_projkv_kernel(
    const short* __restrict__ Ay, const short* __restrict__ Az,
    const short* __restrict__ Bd, const short* __restrict__ Be,
    const float* __restrict__ dbk, const float* __restrict__ dbv,
    const float* __restrict__ ebk, const float* __restrict__ ebv,
    short* __restrict__ Kd, short* __restrict__ Vd,
    short* __restrict__ Ke, short* __restrict__ Ve)
{
    __shared__ short As[64*32];
    __shared__ short Bs[128*32];
    int z = blockIdx.z; int enc = z>>3; int zl = z&7;
    const short* A  = enc ? Az : Ay;
    const short* Bb = (enc ? Be : Bd) + zl*65536;
    const float* b1 = enc ? ebk : dbk;
    const float* b2 = enc ? ebv : dbv;
    short* o1 = enc ? Ke : Kd;
    short* o2 = enc ? Ve : Vd;
    int m0 = blockIdx.x*64;
    int tid = threadIdx.x, wave = tid>>6, lane = tid&63, quad = lane>>4, nl = lane&15;
    int wm = (wave&1)*32, wn = (wave>>1)*64;
    floatx4 acc[2][4];
    #pragma unroll
    for(int i=0;i<2;i++)
        #pragma unroll
        for(int j=0;j<4;j++) acc[i][j] = (floatx4){0.f,0.f,0.f,0.f};
    int r = tid>>2, c = (tid&3)*8;
    for(int k0=0;k0<512;k0+=32){
        __syncthreads();
        __builtin_amdgcn_global_load_lds(
            (const __attribute__((address_space(1))) unsigned*)(A + (long)(m0 + r)*512 + k0 + c),
            (__attribute__((address_space(3))) unsigned*)((char*)As + wave*1024), 16, 0, 0);
        #pragma unroll
        for(int i=0;i<2;i++)
            __builtin_amdgcn_global_load_lds(
                (const __attribute__((address_space(1))) unsigned*)(Bb + (long)(r + i*64)*512 + k0 + c),
                (__attribute__((address_space(3))) unsigned*)((char*)Bs + i*4096 + wave*1024), 16, 0, 0);
        __syncthreads();
        short8 af[2], bfr[4];
        #pragma unroll
        for(int i=0;i<2;i++) af[i] = *(const short8*)(As + (wm + i*16 + nl)*32 + quad*8);
        #pragma unroll
        for(int j=0;j<4;j++) bfr[j] = *(const short8*)(Bs + (wn + j*16 + nl)*32 + quad*8);
        #pragma unroll
        for(int i=0;i<2;i++)
            #pragma unroll
            for(int j=0;j<4;j++)
                acc[i][j] = __builtin_amdgcn_mfma_f32_16x16x32_bf16(af[i],bfr[j],acc[i][j],0,0,0);
    }
    #pragma unroll
    for(int j=0;j<4;j++){
        int n = wn + j*16 + nl;
        float bv = (n >= 64) ? b2[zl*64 + n - 64] : b1[zl*64 + n];
        #pragma unroll
        for(int i=0;i<2;i++){
            #pragma unroll
            for(int rr=0;rr<4;rr++){
                int m = m0 + wm + i*16 + quad*4 + rr;
                float v = acc[i][j][rr] + bv;
                long zb = (long)(zl*NB_ + (m>>10));
                if(n >= 64) o2[ (zb*KD_ + (n-64))*S_ + (m&1023) ] = f2bf(v);
                else        o1[ (zb*S_ + (m&1023))*KD_ + n ] = f2bf(v);
            }
        }
    }
}

// ---------------- projection GEMM for Q ----------------
__global__ __launch_bounds__(256) void gemm_projq_kernel(
    const short* __restrict__ A, const short* __restrict__ Bt,
    const float* __restrict__ b1, short* __restrict__ o1)
{
    __shared__ short As[64*32];
    __shared__ short Bs[64*32];
    int z = blockIdx.z;
    int m0 = blockIdx.x*64;
    const short* Bb = Bt + (long)z*(64*512);
    int tid = threadIdx.x, wave = tid>>6, lane = tid&63, quad = lane>>4, nl = lane&15;
    int wm = (wave&1)*32, wn = (wave>>1)*32;
    floatx4 acc[2][2];
    #pragma unroll
    for(int i=0;i<2;i++)
        #pragma unroll
        for(int j=0;j<2;j++) acc[i][j] = (floatx4){0.f,0.f,0.f,0.f};
    int r = tid>>2, c = (tid&3)*8;
    for(int k0=0;k0<512;k0+=32){
        __syncthreads();
        __builtin_amdgcn_global_load_lds(
            (const __attribute__((address_space(1))) unsigned*)(A + (long)(m0 + r)*512 + k0 + c),
            (__attribute__((address_space(3))) unsigned*)((char*)As + wave*1024), 16, 0, 0);
        __builtin_amdgcn_global_load_lds(
            (const __attribute__((address_space(1))) unsigned*)(Bb + (long)r*512 + k0 + c),
            (__attribute__((address_space(3))) unsigned*)((char*)Bs + wave*1024), 16, 0, 0);
        __syncthreads();
        short8 af[2], bfr[2];
        #pragma unroll
        for(int i=0;i<2;i++) af[i] = *(const short8*)(As + (wm + i*16 + nl)*32 + quad*8);
        #pragma unroll
        for(int j=0;j<2;j++) bfr[j] = *(const short8*)(Bs + (wn + j*16 + nl)*32 + quad*8);
        #pragma unroll
        for(int i=0;i<2;i++)
            #pragma unroll
            for(int j=0;j<2;j++)
                acc[i][j] = __builtin_amdgcn_mfma_f32_16x16x32_bf16(af[i],bfr[j],acc[i][j],0,0,0);
    }
    #pragma unroll
    for(int j=0;j<2;j++){
        int n = wn + j*16 + nl;
        float bv = b1[z*64 + n];
        #pragma unroll
        for(int i=0;i<2;i++){
            #pragma unroll
            for(int rr=0;rr<4;rr++){
                int m = m0 + wm + i*16 + quad*4 + rr;
                float v = acc[i][j][rr] + bv;
                long zb = (long)(z*NB_ + (m>>10));
                o1[ (zb*S_ + (m&1023))*KD_ + n ] = f2bf(v);
            }
        }
    }
}

// ---------------- big MFMA GEMM, m97 pattern ----------------
template<int TM, int TN, int OUTBF, int RELU>
__global__ __launch_bounds__(256) void gemm_big_kernel(
    const short* __restrict__ A, const short* __restrict__ Bt, const float* __restrict__ bias,
    void* __restrict__ out, int M, int N, int K)
{
    __shared__ short As[TM*32];
    __shared__ short Bs[TN*32];
    int m0 = blockIdx.x*TM, n0 = blockIdx.y*TN;
    int tid = threadIdx.x, wave = tid>>6, lane = tid&63, quad = lane>>4, nl = lane&15;
    constexpr int MI = TM/32, NI = TN/32;
    int wm = (wave&1)*(TM/2), wn = (wave>>1)*(TN/2);
    floatx4 acc[MI][NI];
    #pragma unroll
    for(int i=0;i<MI;i++)
        #pragma unroll
        for(int j=0;j<NI;j++) acc[i][j] = (floatx4){0.f,0.f,0.f,0.f};

    int r = tid>>2, c = (tid&3)*8;
    for(int k0=0;k0<K;k0+=32){
        __syncthreads();
        #pragma unroll
        for(int i=0;i<TM/64;i++)
            __builtin_amdgcn_global_load_lds(
                (const __attribute__((address_space(1))) unsigned*)(A + (long)(m0 + r + i*64)*K + k0 + c),
                (__attribute__((address_space(3))) unsigned*)((char*)As + i*4096 + wave*1024),
                16, 0, 0);
        #pragma unroll
        for(int i=0;i<TN/64;i++)
            __builtin_amdgcn_global_load_lds(
                (const __attribute__((address_space(1))) unsigned*)(Bt + (long)(n0 + r + i*64)*K + k0 + c),
                (__attribute__((address_space(3))) unsigned*)((char*)Bs + i*4096 + wave*1024),
                16, 0, 0);
        __syncthreads();
        short8 af[MI], bfr[NI];
        #pragma unroll
        for(int i=0;i<MI;i++) af[i] = *(const short8*)(As + (wm + i*16 + nl)*32 + quad*8);
        #pragma unroll
        for(int j=0;j<NI;j++) bfr[j] = *(const short8*)(Bs + (wn + j*16 + nl)*32 + quad*8);
        #pragma unroll
        for(int i=0;i<MI;i++)
            #pragma unroll
            for(int j=0;j<NI;j++)
                acc[i][j] = __builtin_amdgcn_mfma_f32_16x16x32_bf16(af[i],bfr[j],acc[i][j],0,0,0);
    }
    #pragma unroll
    for(int j=0;j<NI;j++){
        int n = n0 + wn + j*16 + nl;
        float bv = bias[n];
        #pragma unroll
        for(int i=0;i<MI;i++){
            #pragma unroll
            for(int rr=0;rr<4;rr++){
                int m = m0 + wm + i*16 + quad*4 + rr;
                float v = acc[i][j][rr] + bv;
                if(RELU) v = fmaxf(v, 0.f);
                if(OUTBF) ((short*)out)[(long)m*N + n] = f2bf(v);
                else      ((float*)out)[(long)m*N + n] = v;
            }
        }
    }
}

// ---------------- fused attention v12 (round-6 best: bracket + hybrid bisection) ----------------
__global__ __launch_bounds__(512,6) void attn_kernel(
    const short* __restrict__ Qb, const short* __restrict__ Kb, const short* __restrict__ Vt,
    const short* __restrict__ graph, short* __restrict__ ctx, int causal)
{
    __shared__ short attb[16*1024];   // 32 KiB
    __shared__ float pbuf[16*68];     // 4.25 KiB
    int hn = blockIdx.x, qt = blockIdx.y;
    int h = hn>>2, n = hn&3;
    int q0 = qt*16;
    int tid=threadIdx.x, wave=tid>>6, lane=tid&63, quad=lane>>4, nl=lane&15;

    if(causal){
        uint4v fv = (uint4v){0xff80ff80u,0xff80ff80u,0xff80ff80u,0xff80ff80u};
        #pragma unroll
        for(int i=0;i<4;i++) *(uint4v*)((char*)attb + tid*16 + i*8192) = fv;
        __syncthreads();
    }

    // ---- phase 1: scores -> bf16 LDS (rot 8q), diagonal tile masked to -inf ----
    const short* Qp = Qb + ((long)hn*S_ + q0 + nl)*KD_ + quad*8;
    short8 aq0 = *(const short8*)(Qp);
    short8 aq1 = *(const short8*)(Qp + 32);
    const short* Kp = Kb + (long)hn*S_*KD_;
    int stmax = causal ? qt : 63;
    for(int st=wave; st<=stmax; st+=8){
        const short* kp = Kp + (st*16 + nl)*KD_ + quad*8;
        short8 b0 = *(const short8*)(kp);
        short8 b1 = *(const short8*)(kp + 32);
        floatx4 cc = (floatx4){0.f,0.f,0.f,0.f};
        cc = __builtin_amdgcn_mfma_f32_16x16x32_bf16(aq0,b0,cc,0,0,0);
        cc = __builtin_amdgcn_mfma_f32_16x16x32_bf16(aq1,b1,cc,0,0,0);
        int s = st*16 + nl;
        #pragma unroll
        for(int rr=0;rr<4;rr++){
            int q = quad*4 + rr;
            short val = f2bf(cc[rr]*0.125f);
            if(causal && s > q0 + q) val = (short)0xff80;   // -inf
            attb[q*1024 + ((s + 8*q)&1023)] = val;
        }
    }
    __syncthreads();

    // ---- phase 2: top-128 + softmax + graph blend; 2 sequential rows/wave ----
    #pragma unroll 1
    for(int rp=0; rp<2; ++rp){
        int q = wave*2 + rp;
        int qg = q0 + q;
        short* rowp = attb + q*1024;
        int sb = lane*16;
        int p0 = (sb + 8*q) & 1023;
        const short* grow = graph + (long)qg*1024 + sb;
        uint4v g0 = *(const uint4v*)(grow);
        uint4v g1 = *(const uint4v*)(grow + 8);
        uint4v u0 = *(const uint4v*)(rowp + p0);
        uint4v u1 = *(const uint4v*)(rowp + ((p0+8)&1023));
        unsigned pr[8];
        #pragma unroll
        for(int i=0;i<4;i++){ pr[i] = u0[i]; pr[4+i] = u1[i]; }
        unsigned kv[16];
        #pragma unroll
        for(int i=0;i<8;i++){
            unsigned u = pr[i];
            unsigned kp = u ^ (0x80008000u + ((u>>15)&0x00010001u)*0x7fffu);
            kv[2*i]   = kp & 0xffffu;
            kv[2*i+1] = kp >> 16;
        }
        unsigned a0 = umaxu(kv[0],kv[1]),  a1 = umaxu(kv[2],kv[3]);
        unsigned a2 = umaxu(kv[4],kv[5]),  a3 = umaxu(kv[6],kv[7]);
        unsigned a4 = umaxu(kv[8],kv[9]),  a5 = umaxu(kv[10],kv[11]);
        unsigned a6 = umaxu(kv[12],kv[13]),a7 = umaxu(kv[14],kv[15]);
        unsigned mk = umaxu(umaxu(umaxu(a0,a1),umaxu(a2,a3)), umaxu(umaxu(a4,a5),umaxu(a6,a7)));
        unsigned mks = wmax_dpp_u(mk);
        unsigned lmin = wmin_dpp_u(mk);
        // bracket-establishing probe at lmin
        unsigned lo, hi;
        {
            unsigned cnt = count128(kv, lmin);
            if(cnt >= 128u){ lo = lmin; hi = (cnt == 128u) ? (lmin + 1u) : (mks + 1u); }
            else           { lo = 0u;   hi = lmin; }
        }
        // bisection: largest m with count(key >= m) >= 128
        while(hi - lo > 1u){
            unsigned mid = (lo + hi) >> 1;
            unsigned cnt = count128(kv, mid);
            if(cnt >= 128u){ lo = mid; if(cnt == 128u) break; }
            else hi = mid;
        }
        // row max as float (uniform)
        unsigned uo = (mks & 0x8000u) ? ((mks & 0x7fffu)<<16) : ((~mks)<<16);
        float mxf = __builtin_bit_cast(float, uo);
        float ev[16]; float sm = 0.f;
        #pragma unroll
        for(int i=0;i<8;i++){
            float f0 = __builtin_bit_cast(float, pr[i] << 16);
            float f1 = __builtin_bit_cast(float, pr[i] & 0xffff0000u);
            float e0 = __expf(f0 - mxf);
            float e1 = __expf(f1 - mxf);
            e0 = (kv[2*i]   >= lo) ? e0 : 0.f;
            e1 = (kv[2*i+1] >= lo) ? e1 : 0.f;
            ev[2*i] = e0; ev[2*i+1] = e1;
            sm += e0 + e1;
        }
        sm = wsum_dpp_f(sm);
        float inv = 0.5f / sm;   // (1-gw) = 0.5; graph holds 0.5*softmax
        uint4v w0, w1;
        #pragma unroll
        for(int i=0;i<4;i++){
            float gl0 = __builtin_bit_cast(float, g0[i] << 16);
            float gh0 = __builtin_bit_cast(float, g0[i] & 0xffff0000u);
            w0[i] = cvt_pk_bf16(fmaf(ev[2*i], inv, gl0), fmaf(ev[2*i+1], inv, gh0));
            float gl1 = __builtin_bit_cast(float, g1[i] << 16);
            float gh1 = __builtin_bit_cast(float, g1[i] & 0xffff0000u);
            w1[i] = cvt_pk_bf16(fmaf(ev[8+2*i], inv, gl1), fmaf(ev[8+2*i+1], inv, gh1));
        }
        *(uint4v*)(rowp + p0) = w0;
        *(uint4v*)(rowp + ((p0+8)&1023)) = w1;
    }
    __syncthreads();

    // ---- phase 3: ctx = att @ V, split over s-halves (sh), v-quarters (vh) ----
    int vh = wave & 3, sh = wave >> 2;
    int v0 = vh*16;
    const short* Vp = Vt + ((long)hn*KD_ + v0 + nl)*S_;
    floatx4 o4 = (floatx4){0.f,0.f,0.f,0.f};
    int arow = nl;
    int sbase = sh*512;
    for(int s0=sbase; s0<sbase+512; s0+=32){
        int cs = (s0 + quad*8 + 8*arow) & 1023;
        short8 ap = *(const short8*)(attb + arow*1024 + cs);
        short8 bv = *(const short8*)(Vp + s0 + quad*8);
        o4 = __builtin_amdgcn_mfma_f32_16x16x32_bf16(ap,bv,o4,0,0,0);
    }
    if(sh==1){
        #pragma unroll
        for(int rr=0;rr<4;rr++) pbuf[(quad*4+rr)*68 + v0 + nl] = o4[rr];
    }
    __syncthreads();
    if(sh==0){
        #pragma unroll
        for(int rr=0;rr<4;rr++){
            int q = quad*4 + rr;
            float v = o4[rr] + pbuf[q*68 + v0 + nl];
            ctx[ ((long)(n*S_ + q0 + q))*512 + h*KD_ + v0 + nl ] = f2bf(v);
        }
    }
}

// ---------------- LayerNorm(x + res) ----------------
__global__ __launch_bounds__(256) void ln_kernel(const float* __restrict__ x, const float* __restrict__ res,
                                                 float* __restrict__ outf, short* __restrict__ outb){
    long row = blockIdx.x;
    const float* xr = x + row*D_;
    const float* rr = res + row*D_;
    int tid = threadIdx.x, wave = tid>>6, lane = tid&63;
    float t0 = xr[tid] + rr[tid];
    float t1 = xr[tid+256] + rr[tid+256];
    float s = t0 + t1, s2 = t0*t0 + t1*t1;
    __shared__ float red[8];
    s = wred_addf(s); s2 = wred_addf(s2);
    if(lane==0){ red[wave] = s; red[4+wave] = s2; }
    __syncthreads();
    s  = red[0]+red[1]+red[2]+red[3];
    s2 = red[4]+red[5]+red[6]+red[7];
    float mean = s*(1.f/512.f);
    float var = s2*(1.f/512.f) - mean*mean;
    float rs = rsqrtf(var + 1e-5f);
    float o0 = (t0-mean)*rs, o1 = (t1-mean)*rs;
    if(outf){ outf[row*D_+tid] = o0; outf[row*D_+tid+256] = o1; }
    if(outb){ outb[row*D_+tid] = f2bf(o0); outb[row*D_+tid+256] = f2bf(o1); }
}

extern "C" void kernel_launch(void* const* d_in, const int* in_sizes, int n_in,
                              void* d_out, int out_size, void* d_ws, size_t ws_size,
                              hipStream_t stream)
{
    const float* z         = (const float*)d_in[0];
    const float* y         = (const float*)d_in[1];
    const float* graph_dec = (const float*)d_in[2];
    const float* graph_enc = (const float*)d_in[3];
    const float* dec_Wk = (const float*)d_in[4];  const float* dec_bk = (const float*)d_in[5];
    const float* dec_Wv = (const float*)d_in[6];  const float* dec_bv = (const float*)d_in[7];
    const float* dec_Wo = (const float*)d_in[8];  const float* dec_bo = (const float*)d_in[9];
    const float* enc_Wk = (const float*)d_in[10]; const float* enc_bk = (const float*)d_in[11];
    const float* enc_Wq = (const float*)d_in[12]; const float* enc_bq = (const float*)d_in[13];
    const float* enc_Wv = (const float*)d_in[14]; const float* enc_bv = (const float*)d_in[15];
    const float* enc_Wo = (const float*)d_in[16]; const float* enc_bo = (const float*)d_in[17];
    const float* fc_W1  = (const float*)d_in[18]; const float* fc_b1  = (const float*)d_in[19];
    const float* fc_W2  = (const float*)d_in[20]; const float* fc_b2  = (const float*)d_in[21];

    char* ws = (char*)d_ws;
    short* gdec  = (short*)(ws + 0x0000000);
    short* genc  = (short*)(ws + 0x0400000);
    short* y_bf  = (short*)(ws + 0x0800000);
    short* z_bf  = (short*)(ws + 0x0C00000);
    short* Kdec  = (short*)(ws + 0x1000000);
    short* Vtdec = (short*)(ws + 0x1400000);
    short* Kenc  = (short*)(ws + 0x1800000);
    short* Vtenc = (short*)(ws + 0x1C00000);
    short* Qenc  = (short*)(ws + 0x2000000);
    short* ctx   = (short*)(ws + 0x2400000);
    float* tmp   = (float*)(ws + 0x2800000);
    float* hbuf  = (float*)(ws + 0x3000000);
    short* h_bf  = (short*)(ws + 0x3800000);
    float* h2    = (float*)(ws + 0x3C00000);
    short* h2_bf = (short*)(ws + 0x4400000);
    short* fc1   = (short*)(ws + 0x4800000);
    short* wKVd  = (short*)(ws + 0x5800000);
    short* wKVe  = (short*)(ws + 0x5900000);
    short* wQet  = (short*)(ws + 0x5A00000);
    short* wOdt  = (short*)(ws + 0x5A80000);
    short* wOet  = (short*)(ws + 0x5B00000);
    short* wF1t  = (short*)(ws + 0x5B80000);
    short* wF2t  = (short*)(ws + 0x5D80000);
    float* outp  = (float*)d_out;

    dim3 B(256);
    // 1) all preprocessing in one dispatch
    prep_kernel<<<dim3(9984),B,0,stream>>>(
        dec_Wk, dec_Wv, enc_Wk, enc_Wv, enc_Wq, dec_Wo, enc_Wo, fc_W1, fc_W2,
        y, z, graph_dec, graph_enc,
        wKVd, wKVe, wQet, wOdt, wOet, wF1t, wF2t, y_bf, z_bf, gdec, genc);
    // 2) dec + enc KV projections in one dispatch
    gemm_projkv_kernel<<<dim3(64,1,16),B,0,stream>>>(
        y_bf, z_bf, wKVd, wKVe, dec_bk, dec_bv, enc_bk, enc_bv,
        Kdec, Vtdec, Kenc, Vtenc);
    // 3) decoder stage
    attn_kernel<<<dim3(32,64),dim3(512),0,stream>>>(Kdec, Kdec, Vtdec, gdec, ctx, 1);
    gemm_big_kernel<64,128,0,0><<<dim3(64,4),B,0,stream>>>(ctx, wOdt, dec_bo, tmp, 4096, 512, 512);
    ln_kernel<<<dim3(4096),B,0,stream>>>(tmp, y, hbuf, h_bf);
    // 4) encoder-decoder stage
    gemm_projq_kernel<<<dim3(64,1,8),B,0,stream>>>(h_bf, wQet, enc_bq, Qenc);
    attn_kernel<<<dim3(32,64),dim3(512),0,stream>>>(Qenc, Kenc, Vtenc, genc, ctx, 0);
    gemm_big_kernel<64,128,0,0><<<dim3(64,4),B,0,stream>>>(ctx, wOet, enc_bo, tmp, 4096, 512, 512);
    ln_kernel<<<dim3(4096),B,0,stream>>>(tmp, hbuf, h2, h2_bf);
    // 5) MLP
    gemm_big_kernel<128,128,1,1><<<dim3(32,16),B,0,stream>>>(h2_bf, wF1t, fc_b1, fc1, 4096, 2048, 512);
    gemm_big_kernel<64,128,0,0><<<dim3(64,4),B,0,stream>>>(fc1, wF2t, fc_b2, tmp, 4096, 512, 2048);
    ln_kernel<<<dim3(4096),B,0,stream>>>(tmp, h2, outp, (short*)0);
}

// Round 9
// 374.013 us; speedup vs baseline: 1.1167x; 1.0062x over previous
//
#include <hip/hip_runtime.h>
#include <stdint.h>

typedef short short8 __attribute__((ext_vector_type(8)));
typedef short short4v __attribute__((ext_vector_type(4)));
typedef float floatx4 __attribute__((ext_vector_type(4)));
typedef unsigned uint4v __attribute__((ext_vector_type(4)));

#define H_  8
#define NB_ 4      // batch N
#define S_  1024
#define D_  512
#define KD_ 64

// fused "wait for prefetched global->LDS loads, then block barrier"
#define VM0_BARRIER() asm volatile("s_waitcnt vmcnt(0)\n\ts_barrier" ::: "memory")

__device__ __forceinline__ short f2bf(float f){
    unsigned u = __builtin_bit_cast(unsigned, f);
    u += 0x7fffu + ((u>>16)&1u);
    return (short)(u>>16);
}
__device__ __forceinline__ float wred_addf(float x){
    #pragma unroll
    for(int o=32;o>0;o>>=1) x += __shfl_xor(x,o,64);
    return x;
}
__device__ __forceinline__ float wred_maxf(float x){
    #pragma unroll
    for(int o=32;o>0;o>>=1) x = fmaxf(x,__shfl_xor(x,o,64));
    return x;
}
__device__ __forceinline__ unsigned umaxu(unsigned a, unsigned b){ return a>b?a:b; }
__device__ __forceinline__ unsigned uminu(unsigned a, unsigned b){ return a<b?a:b; }

// DPP-based wave64 reductions: pure VALU, result uniform via readlane.
template<int CTRL, int RMASK, int BC>
__device__ __forceinline__ unsigned dppu(unsigned x){
    return (unsigned)__builtin_amdgcn_update_dpp(0, (int)x, CTRL, RMASK, 0xf, BC);
}
template<int CTRL, int RMASK>
__device__ __forceinline__ unsigned dppu_m1(unsigned x){
    return (unsigned)__builtin_amdgcn_update_dpp((int)0xFFFFFFFF, (int)x, CTRL, RMASK, 0xf, 0);
}
__device__ __forceinline__ unsigned wsum_dpp_u(unsigned x){
    x += dppu<0x111,0xf,1>(x);
    x += dppu<0x112,0xf,1>(x);
    x += dppu<0x114,0xf,1>(x);
    x += dppu<0x118,0xf,1>(x);
    x += dppu<0x142,0xa,0>(x);
    x += dppu<0x143,0xc,0>(x);
    return (unsigned)__builtin_amdgcn_readlane((int)x, 63);
}
__device__ __forceinline__ unsigned wmax_dpp_u(unsigned x){
    x = umaxu(x, dppu<0x111,0xf,1>(x));
    x = umaxu(x, dppu<0x112,0xf,1>(x));
    x = umaxu(x, dppu<0x114,0xf,1>(x));
    x = umaxu(x, dppu<0x118,0xf,1>(x));
    x = umaxu(x, dppu<0x142,0xa,0>(x));
    x = umaxu(x, dppu<0x143,0xc,0>(x));
    return (unsigned)__builtin_amdgcn_readlane((int)x, 63);
}
__device__ __forceinline__ unsigned wmin_dpp_u(unsigned x){
    x = uminu(x, dppu_m1<0x111,0xf>(x));
    x = uminu(x, dppu_m1<0x112,0xf>(x));
    x = uminu(x, dppu_m1<0x114,0xf>(x));
    x = uminu(x, dppu_m1<0x118,0xf>(x));
    x = uminu(x, dppu_m1<0x142,0xa>(x));
    x = uminu(x, dppu_m1<0x143,0xc>(x));
    return (unsigned)__builtin_amdgcn_readlane((int)x, 63);
}
__device__ __forceinline__ float addu_f(float a, unsigned b){
    return a + __builtin_bit_cast(float, b);
}
__device__ __forceinline__ float wsum_dpp_f(float x){
    x = addu_f(x, dppu<0x111,0xf,1>(__builtin_bit_cast(unsigned,x)));
    x = addu_f(x, dppu<0x112,0xf,1>(__builtin_bit_cast(unsigned,x)));
    x = addu_f(x, dppu<0x114,0xf,1>(__builtin_bit_cast(unsigned,x)));
    x = addu_f(x, dppu<0x118,0xf,1>(__builtin_bit_cast(unsigned,x)));
    x = addu_f(x, dppu<0x142,0xa,0>(__builtin_bit_cast(unsigned,x)));
    x = addu_f(x, dppu<0x143,0xc,0>(__builtin_bit_cast(unsigned,x)));
    return __builtin_bit_cast(float, (unsigned)__builtin_amdgcn_readlane((int)__builtin_bit_cast(unsigned, x), 63));
}
__device__ __forceinline__ unsigned cvt_pk_bf16(float a, float b){
    unsigned r;
    asm("v_cvt_pk_bf16_f32 %0, %1, %2" : "=v"(r) : "v"(a), "v"(b));
    return r;
}
// hybrid top-k probe count: 8 elements on VALU (addc + DPP reduce),
// 8 elements on SALU (ballot + popcount).
__device__ __forceinline__ unsigned count128(const unsigned (&kv)[16], unsigned mid){
    unsigned cv = 0u;
    #pragma unroll
    for(int j=0;j<8;j++) cv += (unsigned)(kv[j] >= mid);
    unsigned cs = 0u;
    #pragma unroll
    for(int j=8;j<16;j++) cs += (unsigned)__popcll(__ballot(kv[j] >= mid));
    return wsum_dpp_u(cv) + cs;
}

// ---------------- merged prep: wtrans5 + wtrans4 + cvt2 + graph softmax ----------------
__global__ __launch_bounds__(256) void prep_kernel(
    const float* __restrict__ dWk, const float* __restrict__ dWv,
    const float* __restrict__ eWk, const float* __restrict__ eWv, const float* __restrict__ eWq,
    const float* __restrict__ dWo, const float* __restrict__ eWo,
    const float* __restrict__ W1, const float* __restrict__ W2,
    const float* __restrict__ y, const float* __restrict__ z,
    const float* __restrict__ g0, const float* __restrict__ g1,
    short* __restrict__ wKVd, short* __restrict__ wKVe, short* __restrict__ wQet,
    short* __restrict__ oWod, short* __restrict__ oWoe,
    short* __restrict__ oW1, short* __restrict__ oW2,
    short* __restrict__ y_bf, short* __restrict__ z_bf,
    short* __restrict__ og0, short* __restrict__ og1)
{
    __shared__ float t[32][33];
    int id = blockIdx.x;
    int tid = threadIdx.x;
    if(id < 1280){
        // wtrans5: per-head [512][64] -> [64][512] bf16
        int zz = id >> 5; int rem = id & 31; int by = rem >> 1, bx = rem & 1;
        int w = zz>>3, h = zz&7;
        const float* src; short* dst;
        if(w==0){ src = dWk + h*32768; dst = wKVd + h*65536; }
        else if(w==1){ src = dWv + h*32768; dst = wKVd + h*65536 + 32768; }
        else if(w==2){ src = eWk + h*32768; dst = wKVe + h*65536; }
        else if(w==3){ src = eWv + h*32768; dst = wKVe + h*65536 + 32768; }
        else { src = eWq + h*32768; dst = wQet + h*32768; }
        int c0 = bx*32, r0 = by*32;
        int r = tid>>3, cq = (tid&7)*4;
        #pragma unroll
        for(int i=0;i<4;i++) t[r][cq+i] = src[(r0+r)*64 + c0+cq+i];
        __syncthreads();
        int c = tid>>3, rq = (tid&7)*4;
        #pragma unroll
        for(int i=0;i<4;i++) dst[(c0+c)*512 + r0+rq+i] = f2bf(t[rq+i][c]);
    } else if(id < 3840){
        // wtrans4
        int id2 = id - 1280;
        const float* src; short* dst; int R, C, c0, r0;
        if(id2 < 512){
            src = (id2<256)? dWo : eWo; dst = (id2<256)? oWod : oWoe;
            int tt = id2 & 255; R = 512; C = 512;
            c0 = (tt&15)*32; r0 = (tt>>4)*32;
        } else if(id2 < 1536){
            src = W1; dst = oW1; int tt = id2 - 512; R = 512; C = 2048;
            c0 = (tt&63)*32; r0 = (tt>>6)*32;
        } else {
            src = W2; dst = oW2; int tt = id2 - 1536; R = 2048; C = 512;
            c0 = (tt&15)*32; r0 = (tt>>4)*32;
        }
        int r = tid>>3, cq = (tid&7)*4;
        #pragma unroll
        for(int i=0;i<4;i++) t[r][cq+i] = src[(long)(r0+r)*C + c0+cq+i];
        __syncthreads();
        int c = tid>>3, rq = (tid&7)*4;
        #pragma unroll
        for(int i=0;i<4;i++) dst[(long)(c0+c)*R + r0+rq+i] = f2bf(t[rq+i][c]);
    } else if(id < 7936){
        // cvt2: fp32 -> bf16 for y and z
        int tt = id - 3840;
        int bx = tt & 2047, by = tt >> 11;
        const float* in = by ? z : y;
        short* out = by ? z_bf : y_bf;
        int i = (bx*256 + tid)*4;
        floatx4 v = *(const floatx4*)(in + i);
        short4v r;
        #pragma unroll
        for(int j=0;j<4;j++) r[j] = f2bf(v[j]);
        *(short4v*)(out + i) = r;
    } else {
        // graph softmax -> 0.5*softmax bf16
        int tt = id - 7936;
        int row = tt & 1023, by = tt >> 10;
        const float* g = by ? g1 : g0;
        short* o = by ? og1 : og0;
        const float* gr = g + (long)row*S_;
        short* orow = o + (long)row*S_;
        int wave = tid>>6, lane = tid&63;
        float* red = &t[0][0];
        float v[4]; float mx = -3.0e38f;
        #pragma unroll
        for(int i=0;i<4;i++){ v[i] = gr[tid + 256*i]; mx = fmaxf(mx, v[i]); }
        mx = wred_maxf(mx);
        if(lane==0) red[wave] = mx;
        __syncthreads();
        mx = fmaxf(fmaxf(red[0],red[1]), fmaxf(red[2],red[3]));
        float s = 0.f;
        #pragma unroll
        for(int i=0;i<4;i++){ v[i] = __expf(v[i]-mx); s += v[i]; }
        s = wred_addf(s);
        if(lane==0) red[4+wave] = s;
        __syncthreads();
        s = red[4]+red[5]+red[6]+red[7];
        float inv = 0.5f/s;
        #pragma unroll
        for(int i=0;i<4;i++) orow[tid + 256*i] = f2bf(v[i]*inv);
    }
}

// ---------------- merged dec+enc KV projection (2-phase double-buffered) ----------------
__global__ __launch_bounds__(256) void gemm_projkv_kernel(
    const short* __restrict__ Ay, const short* __restrict__ Az,
    const short* __restrict__ Bd, const short* __restrict__ Be,
    const float* __restrict__ dbk, const float* __restrict__ dbv,
    const float* __restrict__ ebk, const float* __restrict__ ebv,
    short* __restrict__ Kd, short* __restrict__ Vd,
    short* __restrict__ Ke, short* __restrict__ Ve)
{
    __shared__ short As[2][64*32];
    __shared__ short Bs[2][128*32];
    int z = blockIdx.z; int enc = z>>3; int zl = z&7;
    const short* A  = enc ? Az : Ay;
    const short* Bb = (enc ? Be : Bd) + zl*65536;
    const float* b1 = enc ? ebk : dbk;
    const float* b2 = enc ? ebv : dbv;
    short* o1 = enc ? Ke : Kd;
    short* o2 = enc ? Ve : Vd;
    int m0 = blockIdx.x*64;
    int tid = threadIdx.x, wave = tid>>6, lane = tid&63, quad = lane>>4, nl = lane&15;
    int wm = (wave&1)*32, wn = (wave>>1)*64;
    floatx4 acc[2][4];
    #pragma unroll
    for(int i=0;i<2;i++)
        #pragma unroll
        for(int j=0;j<4;j++) acc[i][j] = (floatx4){0.f,0.f,0.f,0.f};
    int r = tid>>2, c = (tid&3)*8;
    auto stage = [&](int b, int k0){
        __builtin_amdgcn_global_load_lds(
            (const __attribute__((address_space(1))) unsigned*)(A + (long)(m0 + r)*512 + k0 + c),
            (__attribute__((address_space(3))) unsigned*)((char*)As[b] + wave*1024), 16, 0, 0);
        #pragma unroll
        for(int i=0;i<2;i++)
            __builtin_amdgcn_global_load_lds(
                (const __attribute__((address_space(1))) unsigned*)(Bb + (long)(r + i*64)*512 + k0 + c),
                (__attribute__((address_space(3))) unsigned*)((char*)Bs[b] + i*4096 + wave*1024), 16, 0, 0);
    };
    stage(0, 0);
    VM0_BARRIER();
    int cur = 0;
    for(int k0=0;k0<512;k0+=32){
        if(k0 + 32 < 512) stage(cur^1, k0+32);
        short8 af[2], bfr[4];
        #pragma unroll
        for(int i=0;i<2;i++) af[i] = *(const short8*)(As[cur] + (wm + i*16 + nl)*32 + quad*8);
        #pragma unroll
        for(int j=0;j<4;j++) bfr[j] = *(const short8*)(Bs[cur] + (wn + j*16 + nl)*32 + quad*8);
        #pragma unroll
        for(int i=0;i<2;i++)
            #pragma unroll
            for(int j=0;j<4;j++)
                acc[i][j] = __builtin_amdgcn_mfma_f32_16x16x32_bf16(af[i],bfr[j],acc[i][j],0,0,0);
        VM0_BARRIER();
        cur ^= 1;
    }
    #pragma unroll
    for(int j=0;j<4;j++){
        int n = wn + j*16 + nl;
        float bv = (n >= 64) ? b2[zl*64 + n - 64] : b1[zl*64 + n];
        #pragma unroll
        for(int i=0;i<2;i++){
            #pragma unroll
            for(int rr=0;rr<4;rr++){
                int m = m0 + wm + i*16 + quad*4 + rr;
                float v = acc[i][j][rr] + bv;
                long zb = (long)(zl*NB_ + (m>>10));
                if(n >= 64) o2[ (zb*KD_ + (n-64))*S_ + (m&1023) ] = f2bf(v);
                else        o1[ (zb*S_ + (m&1023))*KD_ + n ] = f2bf(v);
            }
        }
    }
}

// ---------------- projection GEMM for Q (2-phase double-buffered) ----------------
__global__ __launch_bounds__(256) void gemm_projq_kernel(
    const short* __restrict__ A, const short* __restrict__ Bt,
    const float* __restrict__ b1, short* __restrict__ o1)
{
    __shared__ short As[2][64*32];
    __shared__ short Bs[2][64*32];
    int z = blockIdx.z;
    int m0 = blockIdx.x*64;
    const short* Bb = Bt + (long)z*(64*512);
    int tid = threadIdx.x, wave = tid>>6, lane = tid&63, quad = lane>>4, nl = lane&15;
    int wm = (wave&1)*32, wn = (wave>>1)*32;
    floatx4 acc[2][2];
    #pragma unroll
    for(int i=0;i<2;i++)
        #pragma unroll
        for(int j=0;j<2;j++) acc[i][j] = (floatx4){0.f,0.f,0.f,0.f};
    int r = tid>>2, c = (tid&3)*8;
    auto stage = [&](int b, int k0){
        __builtin_amdgcn_global_load_lds(
            (const __attribute__((address_space(1))) unsigned*)(A + (long)(m0 + r)*512 + k0 + c),
            (__attribute__((address_space(3))) unsigned*)((char*)As[b] + wave*1024), 16, 0, 0);
        __builtin_amdgcn_global_load_lds(
            (const __attribute__((address_space(1))) unsigned*)(Bb + (long)r*512 + k0 + c),
            (__attribute__((address_space(3))) unsigned*)((char*)Bs[b] + wave*1024), 16, 0, 0);
    };
    stage(0, 0);
    VM0_BARRIER();
    int cur = 0;
    for(int k0=0;k0<512;k0+=32){
        if(k0 + 32 < 512) stage(cur^1, k0+32);
        short8 af[2], bfr[2];
        #pragma unroll
        for(int i=0;i<2;i++) af[i] = *(const short8*)(As[cur] + (wm + i*16 + nl)*32 + quad*8);
        #pragma unroll
        for(int j=0;j<2;j++) bfr[j] = *(const short8*)(Bs[cur] + (wn + j*16 + nl)*32 + quad*8);
        #pragma unroll
        for(int i=0;i<2;i++)
            #pragma unroll
            for(int j=0;j<2;j++)
                acc[i][j] = __builtin_amdgcn_mfma_f32_16x16x32_bf16(af[i],bfr[j],acc[i][j],0,0,0);
        VM0_BARRIER();
        cur ^= 1;
    }
    #pragma unroll
    for(int j=0;j<2;j++){
        int n = wn + j*16 + nl;
        float bv = b1[z*64 + n];
        #pragma unroll
        for(int i=0;i<2;i++){
            #pragma unroll
            for(int rr=0;rr<4;rr++){
                int m = m0 + wm + i*16 + quad*4 + rr;
                float v = acc[i][j][rr] + bv;
                long zb = (long)(z*NB_ + (m>>10));
                o1[ (zb*S_ + (m&1023))*KD_ + n ] = f2bf(v);
            }
        }
    }
}

// ---------------- big MFMA GEMM, m97 pattern, 2-phase double-buffered ----------------
template<int TM, int TN, int OUTBF, int RELU>
__global__ __launch_bounds__(256) void gemm_big_kernel(
    const short* __restrict__ A, const short* __restrict__ Bt, const float* __restrict__ bias,
    void* __restrict__ out, int M, int N, int K)
{
    __shared__ short As[2][TM*32];
    __shared__ short Bs[2][TN*32];
    int m0 = blockIdx.x*TM, n0 = blockIdx.y*TN;
    int tid = threadIdx.x, wave = tid>>6, lane = tid&63, quad = lane>>4, nl = lane&15;
    constexpr int MI = TM/32, NI = TN/32;
    int wm = (wave&1)*(TM/2), wn = (wave>>1)*(TN/2);
    floatx4 acc[MI][NI];
    #pragma unroll
    for(int i=0;i<MI;i++)
        #pragma unroll
        for(int j=0;j<NI;j++) acc[i][j] = (floatx4){0.f,0.f,0.f,0.f};

    int r = tid>>2, c = (tid&3)*8;
    auto stage = [&](int b, int k0){
        #pragma unroll
        for(int i=0;i<TM/64;i++)
            __builtin_amdgcn_global_load_lds(
                (const __attribute__((address_space(1))) unsigned*)(A + (long)(m0 + r + i*64)*K + k0 + c),
                (__attribute__((address_space(3))) unsigned*)((char*)As[b] + i*4096 + wave*1024),
                16, 0, 0);
        #pragma unroll
        for(int i=0;i<TN/64;i++)
            __builtin_amdgcn_global_load_lds(
                (const __attribute__((address_space(1))) unsigned*)(Bt + (long)(n0 + r + i*64)*K + k0 + c),
                (__attribute__((address_space(3))) unsigned*)((char*)Bs[b] + i*4096 + wave*1024),
                16, 0, 0);
    };
    stage(0, 0);
    VM0_BARRIER();
    int cur = 0;
    for(int k0=0;k0<K;k0+=32){
        if(k0 + 32 < K) stage(cur^1, k0+32);
        short8 af[MI], bfr[NI];
        #pragma unroll
        for(int i=0;i<MI;i++) af[i] = *(const short8*)(As[cur] + (wm + i*16 + nl)*32 + quad*8);
        #pragma unroll
        for(int j=0;j<NI;j++) bfr[j] = *(const short8*)(Bs[cur] + (wn + j*16 + nl)*32 + quad*8);
        #pragma unroll
        for(int i=0;i<MI;i++)
            #pragma unroll
            for(int j=0;j<NI;j++)
                acc[i][j] = __builtin_amdgcn_mfma_f32_16x16x32_bf16(af[i],bfr[j],acc[i][j],0,0,0);
        VM0_BARRIER();
        cur ^= 1;
    }
    #pragma unroll
    for(int j=0;j<NI;j++){
        int n = n0 + wn + j*16 + nl;
        float bv = bias[n];
        #pragma unroll
        for(int i=0;i<MI;i++){
            #pragma unroll
            for(int rr=0;rr<4;rr++){
                int m = m0 + wm + i*16 + quad*4 + rr;
                float v = acc[i][j][rr] + bv;
                if(RELU) v = fmaxf(v, 0.f);
                if(OUTBF) ((short*)out)[(long)m*N + n] = f2bf(v);
                else      ((float*)out)[(long)m*N + n] = v;
            }
        }
    }
}

// ---------------- fused attention v12 (round-6 best: bracket + hybrid bisection) ----------------
__global__ __launch_bounds__(512,6) void attn_kernel(
    const short* __restrict__ Qb, const short* __restrict__ Kb, const short* __restrict__ Vt,
    const short* __restrict__ graph, short* __restrict__ ctx, int causal)
{
    __shared__ short attb[16*1024];   // 32 KiB
    __shared__ float pbuf[16*68];     // 4.25 KiB
    int hn = blockIdx.x, qt = blockIdx.y;
    int h = hn>>2, n = hn&3;
    int q0 = qt*16;
    int tid=threadIdx.x, wave=tid>>6, lane=tid&63, quad=lane>>4, nl=lane&15;

    if(causal){
        uint4v fv = (uint4v){0xff80ff80u,0xff80ff80u,0xff80ff80u,0xff80ff80u};
        #pragma unroll
        for(int i=0;i<4;i++) *(uint4v*)((char*)attb + tid*16 + i*8192) = fv;
        __syncthreads();
    }

    // ---- phase 1: scores -> bf16 LDS (rot 8q), diagonal tile masked to -inf ----
    const short* Qp = Qb + ((long)hn*S_ + q0 + nl)*KD_ + quad*8;
    short8 aq0 = *(const short8*)(Qp);
    short8 aq1 = *(const short8*)(Qp + 32);
    const short* Kp = Kb + (long)hn*S_*KD_;
    int stmax = causal ? qt : 63;
    for(int st=wave; st<=stmax; st+=8){
        const short* kp = Kp + (st*16 + nl)*KD_ + quad*8;
        short8 b0 = *(const short8*)(kp);
        short8 b1 = *(const short8*)(kp + 32);
        floatx4 cc = (floatx4){0.f,0.f,0.f,0.f};
        cc = __builtin_amdgcn_mfma_f32_16x16x32_bf16(aq0,b0,cc,0,0,0);
        cc = __builtin_amdgcn_mfma_f32_16x16x32_bf16(aq1,b1,cc,0,0,0);
        int s = st*16 + nl;
        #pragma unroll
        for(int rr=0;rr<4;rr++){
            int q = quad*4 + rr;
            short val = f2bf(cc[rr]*0.125f);
            if(causal && s > q0 + q) val = (short)0xff80;   // -inf
            attb[q*1024 + ((s + 8*q)&1023)] = val;
        }
    }
    __syncthreads();

    // ---- phase 2: top-128 + softmax + graph blend; 2 sequential rows/wave ----
    #pragma unroll 1
    for(int rp=0; rp<2; ++rp){
        int q = wave*2 + rp;
        int qg = q0 + q;
        short* rowp = attb + q*1024;
        int sb = lane*16;
        int p0 = (sb + 8*q) & 1023;
        const short* grow = graph + (long)qg*1024 + sb;
        uint4v g0 = *(const uint4v*)(grow);
        uint4v g1 = *(const uint4v*)(grow + 8);
        uint4v u0 = *(const uint4v*)(rowp + p0);
        uint4v u1 = *(const uint4v*)(rowp + ((p0+8)&1023));
        unsigned pr[8];
        #pragma unroll
        for(int i=0;i<4;i++){ pr[i] = u0[i]; pr[4+i] = u1[i]; }
        unsigned kv[16];
        #pragma unroll
        for(int i=0;i<8;i++){
            unsigned u = pr[i];
            unsigned kp = u ^ (0x80008000u + ((u>>15)&0x00010001u)*0x7fffu);
            kv[2*i]   = kp & 0xffffu;
            kv[2*i+1] = kp >> 16;
        }
        unsigned a0 = umaxu(kv[0],kv[1]),  a1 = umaxu(kv[2],kv[3]);
        unsigned a2 = umaxu(kv[4],kv[5]),  a3 = umaxu(kv[6],kv[7]);
        unsigned a4 = umaxu(kv[8],kv[9]),  a5 = umaxu(kv[10],kv[11]);
        unsigned a6 = umaxu(kv[12],kv[13]),a7 = umaxu(kv[14],kv[15]);
        unsigned mk = umaxu(umaxu(umaxu(a0,a1),umaxu(a2,a3)), umaxu(umaxu(a4,a5),umaxu(a6,a7)));
        unsigned mks = wmax_dpp_u(mk);
        unsigned lmin = wmin_dpp_u(mk);
        // bracket-establishing probe at lmin
        unsigned lo, hi;
        {
            unsigned cnt = count128(kv, lmin);
            if(cnt >= 128u){ lo = lmin; hi = (cnt == 128u) ? (lmin + 1u) : (mks + 1u); }
            else           { lo = 0u;   hi = lmin; }
        }
        // bisection: largest m with count(key >= m) >= 128
        while(hi - lo > 1u){
            unsigned mid = (lo + hi) >> 1;
            unsigned cnt = count128(kv, mid);
            if(cnt >= 128u){ lo = mid; if(cnt == 128u) break; }
            else hi = mid;
        }
        // row max as float (uniform)
        unsigned uo = (mks & 0x8000u) ? ((mks & 0x7fffu)<<16) : ((~mks)<<16);
        float mxf = __builtin_bit_cast(float, uo);
        float ev[16]; float sm = 0.f;
        #pragma unroll
        for(int i=0;i<8;i++){
            float f0 = __builtin_bit_cast(float, pr[i] << 16);
            float f1 = __builtin_bit_cast(float, pr[i] & 0xffff0000u);
            float e0 = __expf(f0 - mxf);
            float e1 = __expf(f1 - mxf);
            e0 = (kv[2*i]   >= lo) ? e0 : 0.f;
            e1 = (kv[2*i+1] >= lo) ? e1 : 0.f;
            ev[2*i] = e0; ev[2*i+1] = e1;
            sm += e0 + e1;
        }
        sm = wsum_dpp_f(sm);
        float inv = 0.5f / sm;   // (1-gw) = 0.5; graph holds 0.5*softmax
        uint4v w0, w1;
        #pragma unroll
        for(int i=0;i<4;i++){
            float gl0 = __builtin_bit_cast(float, g0[i] << 16);
            float gh0 = __builtin_bit_cast(float, g0[i] & 0xffff0000u);
            w0[i] = cvt_pk_bf16(fmaf(ev[2*i], inv, gl0), fmaf(ev[2*i+1], inv, gh0));
            float gl1 = __builtin_bit_cast(float, g1[i] << 16);
            float gh1 = __builtin_bit_cast(float, g1[i] & 0xffff0000u);
            w1[i] = cvt_pk_bf16(fmaf(ev[8+2*i], inv, gl1), fmaf(ev[8+2*i+1], inv, gh1));
        }
        *(uint4v*)(rowp + p0) = w0;
        *(uint4v*)(rowp + ((p0+8)&1023)) = w1;
    }
    __syncthreads();

    // ---- phase 3: ctx = att @ V, split over s-halves (sh), v-quarters (vh) ----
    int vh = wave & 3, sh = wave >> 2;
    int v0 = vh*16;
    const short* Vp = Vt + ((long)hn*KD_ + v0 + nl)*S_;
    floatx4 o4 = (floatx4){0.f,0.f,0.f,0.f};
    int arow = nl;
    int sbase = sh*512;
    for(int s0=sbase; s0<sbase+512; s0+=32){
        int cs = (s0 + quad*8 + 8*arow) & 1023;
        short8 ap = *(const short8*)(attb + arow*1024 + cs);
        short8 bv = *(const short8*)(Vp + s0 + quad*8);
        o4 = __builtin_amdgcn_mfma_f32_16x16x32_bf16(ap,bv,o4,0,0,0);
    }
    if(sh==1){
        #pragma unroll
        for(int rr=0;rr<4;rr++) pbuf[(quad*4+rr)*68 + v0 + nl] = o4[rr];
    }
    __syncthreads();
    if(sh==0){
        #pragma unroll
        for(int rr=0;rr<4;rr++){
            int q = quad*4 + rr;
            float v = o4[rr] + pbuf[q*68 + v0 + nl];
            ctx[ ((long)(n*S_ + q0 + q))*512 + h*KD_ + v0 + nl ] = f2bf(v);
        }
    }
}

// ---------------- LayerNorm(x + res) ----------------
__global__ __launch_bounds__(256) void ln_kernel(const float* __restrict__ x, const float* __restrict__ res,
                                                 float* __restrict__ outf, short* __restrict__ outb){
    long row = blockIdx.x;
    const float* xr = x + row*D_;
    const float* rr = res + row*D_;
    int tid = threadIdx.x, wave = tid>>6, lane = tid&63;
    float t0 = xr[tid] + rr[tid];
    float t1 = xr[tid+256] + rr[tid+256];
    float s = t0 + t1, s2 = t0*t0 + t1*t1;
    __shared__ float red[8];
    s = wred_addf(s); s2 = wred_addf(s2);
    if(lane==0){ red[wave] = s; red[4+wave] = s2; }
    __syncthreads();
    s  = red[0]+red[1]+red[2]+red[3];
    s2 = red[4]+red[5]+red[6]+red[7];
    float mean = s*(1.f/512.f);
    float var = s2*(1.f/512.f) - mean*mean;
    float rs = rsqrtf(var + 1e-5f);
    float o0 = (t0-mean)*rs, o1 = (t1-mean)*rs;
    if(outf){ outf[row*D_+tid] = o0; outf[row*D_+tid+256] = o1; }
    if(outb){ outb[row*D_+tid] = f2bf(o0); outb[row*D_+tid+256] = f2bf(o1); }
}

extern "C" void kernel_launch(void* const* d_in, const int* in_sizes, int n_in,
                              void* d_out, int out_size, void* d_ws, size_t ws_size,
                              hipStream_t stream)
{
    const float* z         = (const float*)d_in[0];
    const float* y         = (const float*)d_in[1];
    const float* graph_dec = (const float*)d_in[2];
    const float* graph_enc = (const float*)d_in[3];
    const float* dec_Wk = (const float*)d_in[4];  const float* dec_bk = (const float*)d_in[5];
    const float* dec_Wv = (const float*)d_in[6];  const float* dec_bv = (const float*)d_in[7];
    const float* dec_Wo = (const float*)d_in[8];  const float* dec_bo = (const float*)d_in[9];
    const float* enc_Wk = (const float*)d_in[10]; const float* enc_bk = (const float*)d_in[11];
    const float* enc_Wq = (const float*)d_in[12]; const float* enc_bq = (const float*)d_in[13];
    const float* enc_Wv = (const float*)d_in[14]; const float* enc_bv = (const float*)d_in[15];
    const float* enc_Wo = (const float*)d_in[16]; const float* enc_bo = (const float*)d_in[17];
    const float* fc_W1  = (const float*)d_in[18]; const float* fc_b1  = (const float*)d_in[19];
    const float* fc_W2  = (const float*)d_in[20]; const float* fc_b2  = (const float*)d_in[21];

    char* ws = (char*)d_ws;
    short* gdec  = (short*)(ws + 0x0000000);
    short* genc  = (short*)(ws + 0x0400000);
    short* y_bf  = (short*)(ws + 0x0800000);
    short* z_bf  = (short*)(ws + 0x0C00000);
    short* Kdec  = (short*)(ws + 0x1000000);
    short* Vtdec = (short*)(ws + 0x1400000);
    short* Kenc  = (short*)(ws + 0x1800000);
    short* Vtenc = (short*)(ws + 0x1C00000);
    short* Qenc  = (short*)(ws + 0x2000000);
    short* ctx   = (short*)(ws + 0x2400000);
    float* tmp   = (float*)(ws + 0x2800000);
    float* hbuf  = (float*)(ws + 0x3000000);
    short* h_bf  = (short*)(ws + 0x3800000);
    float* h2    = (float*)(ws + 0x3C00000);
    short* h2_bf = (short*)(ws + 0x4400000);
    short* fc1   = (short*)(ws + 0x4800000);
    short* wKVd  = (short*)(ws + 0x5800000);
    short* wKVe  = (short*)(ws + 0x5900000);
    short* wQet  = (short*)(ws + 0x5A00000);
    short* wOdt  = (short*)(ws + 0x5A80000);
    short* wOet  = (short*)(ws + 0x5B00000);
    short* wF1t  = (short*)(ws + 0x5B80000);
    short* wF2t  = (short*)(ws + 0x5D80000);
    float* outp  = (float*)d_out;

    dim3 B(256);
    // 1) all preprocessing in one dispatch
    prep_kernel<<<dim3(9984),B,0,stream>>>(
        dec_Wk, dec_Wv, enc_Wk, enc_Wv, enc_Wq, dec_Wo, enc_Wo, fc_W1, fc_W2,
        y, z, graph_dec, graph_enc,
        wKVd, wKVe, wQet, wOdt, wOet, wF1t, wF2t, y_bf, z_bf, gdec, genc);
    // 2) dec + enc KV projections in one dispatch
    gemm_projkv_kernel<<<dim3(64,1,16),B,0,stream>>>(
        y_bf, z_bf, wKVd, wKVe, dec_bk, dec_bv, enc_bk, enc_bv,
        Kdec, Vtdec, Kenc, Vtenc);
    // 3) decoder stage
    attn_kernel<<<dim3(32,64),dim3(512),0,stream>>>(Kdec, Kdec, Vtdec, gdec, ctx, 1);
    gemm_big_kernel<64,128,0,0><<<dim3(64,4),B,0,stream>>>(ctx, wOdt, dec_bo, tmp, 4096, 512, 512);
    ln_kernel<<<dim3(4096),B,0,stream>>>(tmp, y, hbuf, h_bf);
    // 4) encoder-decoder stage
    gemm_projq_kernel<<<dim3(64,1,8),B,0,stream>>>(h_bf, wQet, enc_bq, Qenc);
    attn_kernel<<<dim3(32,64),dim3(512),0,stream>>>(Qenc, Kenc, Vtenc, genc, ctx, 0);
    gemm_big_kernel<64,128,0,0><<<dim3(64,4),B,0,stream>>>(ctx, wOet, enc_bo, tmp, 4096, 512, 512);
    ln_kernel<<<dim3(4096),B,0,stream>>>(tmp, hbuf, h2, h2_bf);
    // 5) MLP
    gemm_big_kernel<128,128,1,1><<<dim3(32,16),B,0,stream>>>(h2_bf, wF1t, fc_b1, fc1, 4096, 2048, 512);
    gemm_big_kernel<64,128,0,0><<<dim3(64,4),B,0,stream>>>(fc1, wF2t, fc_b2, tmp, 4096, 512, 2048);
    ln_kernel<<<dim3(4096),B,0,stream>>>(tmp, h2, outp, (short*)0);
}

// Round 10
// 361.316 us; speedup vs baseline: 1.1559x; 1.0351x over previous
//
#include <hip/hip_runtime.h>
#include <stdint.h>

typedef short short8 __attribute__((ext_vector_type(8)));
typedef short short4v __attribute__((ext_vector_type(4)));
typedef float floatx4 __attribute__((ext_vector_type(4)));
typedef unsigned uint4v __attribute__((ext_vector_type(4)));

#define H_  8
#define NB_ 4      // batch N
#define S_  1024
#define D_  512
#define KD_ 64

// fused "wait for prefetched global->LDS loads, then block barrier"
#define VM0_BARRIER() asm volatile("s_waitcnt vmcnt(0)\n\ts_barrier" ::: "memory")

__device__ __forceinline__ short f2bf(float f){
    unsigned u = __builtin_bit_cast(unsigned, f);
    u += 0x7fffu + ((u>>16)&1u);
    return (short)(u>>16);
}
__device__ __forceinline__ float wred_addf(float x){
    #pragma unroll
    for(int o=32;o>0;o>>=1) x += __shfl_xor(x,o,64);
    return x;
}
__device__ __forceinline__ float wred_maxf(float x){
    #pragma unroll
    for(int o=32;o>0;o>>=1) x = fmaxf(x,__shfl_xor(x,o,64));
    return x;
}
__device__ __forceinline__ unsigned umaxu(unsigned a, unsigned b){ return a>b?a:b; }
__device__ __forceinline__ unsigned uminu(unsigned a, unsigned b){ return a<b?a:b; }

// DPP-based wave64 reductions: pure VALU, result uniform via readlane.
template<int CTRL, int RMASK, int BC>
__device__ __forceinline__ unsigned dppu(unsigned x){
    return (unsigned)__builtin_amdgcn_update_dpp(0, (int)x, CTRL, RMASK, 0xf, BC);
}
template<int CTRL, int RMASK>
__device__ __forceinline__ unsigned dppu_m1(unsigned x){
    return (unsigned)__builtin_amdgcn_update_dpp((int)0xFFFFFFFF, (int)x, CTRL, RMASK, 0xf, 0);
}
__device__ __forceinline__ unsigned wsum_dpp_u(unsigned x){
    x += dppu<0x111,0xf,1>(x);
    x += dppu<0x112,0xf,1>(x);
    x += dppu<0x114,0xf,1>(x);
    x += dppu<0x118,0xf,1>(x);
    x += dppu<0x142,0xa,0>(x);
    x += dppu<0x143,0xc,0>(x);
    return (unsigned)__builtin_amdgcn_readlane((int)x, 63);
}
__device__ __forceinline__ unsigned wmax_dpp_u(unsigned x){
    x = umaxu(x, dppu<0x111,0xf,1>(x));
    x = umaxu(x, dppu<0x112,0xf,1>(x));
    x = umaxu(x, dppu<0x114,0xf,1>(x));
    x = umaxu(x, dppu<0x118,0xf,1>(x));
    x = umaxu(x, dppu<0x142,0xa,0>(x));
    x = umaxu(x, dppu<0x143,0xc,0>(x));
    return (unsigned)__builtin_amdgcn_readlane((int)x, 63);
}
__device__ __forceinline__ unsigned wmin_dpp_u(unsigned x){
    x = uminu(x, dppu_m1<0x111,0xf>(x));
    x = uminu(x, dppu_m1<0x112,0xf>(x));
    x = uminu(x, dppu_m1<0x114,0xf>(x));
    x = uminu(x, dppu_m1<0x118,0xf>(x));
    x = uminu(x, dppu_m1<0x142,0xa>(x));
    x = uminu(x, dppu_m1<0x143,0xc>(x));
    return (unsigned)__builtin_amdgcn_readlane((int)x, 63);
}
__device__ __forceinline__ float addu_f(float a, unsigned b){
    return a + __builtin_bit_cast(float, b);
}
__device__ __forceinline__ float wsum_dpp_f(float x){
    x = addu_f(x, dppu<0x111,0xf,1>(__builtin_bit_cast(unsigned,x)));
    x = addu_f(x, dppu<0x112,0xf,1>(__builtin_bit_cast(unsigned,x)));
    x = addu_f(x, dppu<0x114,0xf,1>(__builtin_bit_cast(unsigned,x)));
    x = addu_f(x, dppu<0x118,0xf,1>(__builtin_bit_cast(unsigned,x)));
    x = addu_f(x, dppu<0x142,0xa,0>(__builtin_bit_cast(unsigned,x)));
    x = addu_f(x, dppu<0x143,0xc,0>(__builtin_bit_cast(unsigned,x)));
    return __builtin_bit_cast(float, (unsigned)__builtin_amdgcn_readlane((int)__builtin_bit_cast(unsigned, x), 63));
}
__device__ __forceinline__ unsigned cvt_pk_bf16(float a, float b){
    unsigned r;
    asm("v_cvt_pk_bf16_f32 %0, %1, %2" : "=v"(r) : "v"(a), "v"(b));
    return r;
}
// hybrid top-k probe count: 8 elements on VALU (addc + DPP reduce),
// 8 elements on SALU (ballot + popcount).
__device__ __forceinline__ unsigned count128(const unsigned (&kv)[16], unsigned mid){
    unsigned cv = 0u;
    #pragma unroll
    for(int j=0;j<8;j++) cv += (unsigned)(kv[j] >= mid);
    unsigned cs = 0u;
    #pragma unroll
    for(int j=8;j<16;j++) cs += (unsigned)__popcll(__ballot(kv[j] >= mid));
    return wsum_dpp_u(cv) + cs;
}

// ---------------- merged prep: wtrans5 + wtrans4 + cvt2 + graph softmax ----------------
__global__ __launch_bounds__(256) void prep_kernel(
    const float* __restrict__ dWk, const float* __restrict__ dWv,
    const float* __restrict__ eWk, const float* __restrict__ eWv, const float* __restrict__ eWq,
    const float* __restrict__ dWo, const float* __restrict__ eWo,
    const float* __restrict__ W1, const float* __restrict__ W2,
    const float* __restrict__ y, const float* __restrict__ z,
    const float* __restrict__ g0, const float* __restrict__ g1,
    short* __restrict__ wKVd, short* __restrict__ wKVe, short* __restrict__ wQet,
    short* __restrict__ oWod, short* __restrict__ oWoe,
    short* __restrict__ oW1, short* __restrict__ oW2,
    short* __restrict__ y_bf, short* __restrict__ z_bf,
    short* __restrict__ og0, short* __restrict__ og1)
{
    __shared__ float t[32][33];
    int id = blockIdx.x;
    int tid = threadIdx.x;
    if(id < 1280){
        // wtrans5: per-head [512][64] -> [64][512] bf16
        int zz = id >> 5; int rem = id & 31; int by = rem >> 1, bx = rem & 1;
        int w = zz>>3, h = zz&7;
        const float* src; short* dst;
        if(w==0){ src = dWk + h*32768; dst = wKVd + h*65536; }
        else if(w==1){ src = dWv + h*32768; dst = wKVd + h*65536 + 32768; }
        else if(w==2){ src = eWk + h*32768; dst = wKVe + h*65536; }
        else if(w==3){ src = eWv + h*32768; dst = wKVe + h*65536 + 32768; }
        else { src = eWq + h*32768; dst = wQet + h*32768; }
        int c0 = bx*32, r0 = by*32;
        int r = tid>>3, cq = (tid&7)*4;
        #pragma unroll
        for(int i=0;i<4;i++) t[r][cq+i] = src[(r0+r)*64 + c0+cq+i];
        __syncthreads();
        int c = tid>>3, rq = (tid&7)*4;
        #pragma unroll
        for(int i=0;i<4;i++) dst[(c0+c)*512 + r0+rq+i] = f2bf(t[rq+i][c]);
    } else if(id < 3840){
        // wtrans4
        int id2 = id - 1280;
        const float* src; short* dst; int R, C, c0, r0;
        if(id2 < 512){
            src = (id2<256)? dWo : eWo; dst = (id2<256)? oWod : oWoe;
            int tt = id2 & 255; R = 512; C = 512;
            c0 = (tt&15)*32; r0 = (tt>>4)*32;
        } else if(id2 < 1536){
            src = W1; dst = oW1; int tt = id2 - 512; R = 512; C = 2048;
            c0 = (tt&63)*32; r0 = (tt>>6)*32;
        } else {
            src = W2; dst = oW2; int tt = id2 - 1536; R = 2048; C = 512;
            c0 = (tt&15)*32; r0 = (tt>>4)*32;
        }
        int r = tid>>3, cq = (tid&7)*4;
        #pragma unroll
        for(int i=0;i<4;i++) t[r][cq+i] = src[(long)(r0+r)*C + c0+cq+i];
        __syncthreads();
        int c = tid>>3, rq = (tid&7)*4;
        #pragma unroll
        for(int i=0;i<4;i++) dst[(long)(c0+c)*R + r0+rq+i] = f2bf(t[rq+i][c]);
    } else if(id < 7936){
        // cvt2: fp32 -> bf16 for y and z
        int tt = id - 3840;
        int bx = tt & 2047, by = tt >> 11;
        const float* in = by ? z : y;
        short* out = by ? z_bf : y_bf;
        int i = (bx*256 + tid)*4;
        floatx4 v = *(const floatx4*)(in + i);
        short4v r;
        #pragma unroll
        for(int j=0;j<4;j++) r[j] = f2bf(v[j]);
        *(short4v*)(out + i) = r;
    } else {
        // graph softmax -> 0.5*softmax bf16
        int tt = id - 7936;
        int row = tt & 1023, by = tt >> 10;
        const float* g = by ? g1 : g0;
        short* o = by ? og1 : og0;
        const float* gr = g + (long)row*S_;
        short* orow = o + (long)row*S_;
        int wave = tid>>6, lane = tid&63;
        float* red = &t[0][0];
        float v[4]; float mx = -3.0e38f;
        #pragma unroll
        for(int i=0;i<4;i++){ v[i] = gr[tid + 256*i]; mx = fmaxf(mx, v[i]); }
        mx = wred_maxf(mx);
        if(lane==0) red[wave] = mx;
        __syncthreads();
        mx = fmaxf(fmaxf(red[0],red[1]), fmaxf(red[2],red[3]));
        float s = 0.f;
        #pragma unroll
        for(int i=0;i<4;i++){ v[i] = __expf(v[i]-mx); s += v[i]; }
        s = wred_addf(s);
        if(lane==0) red[4+wave] = s;
        __syncthreads();
        s = red[4]+red[5]+red[6]+red[7];
        float inv = 0.5f/s;
        #pragma unroll
        for(int i=0;i<4;i++) orow[tid + 256*i] = f2bf(v[i]*inv);
    }
}

// ---------------- merged dec+enc KV projection (2-phase double-buffered) ----------------
__global__ __launch_bounds__(256) void gemm_projkv_kernel(
    const short* __restrict__ Ay, const short* __restrict__ Az,
    const short* __restrict__ Bd, const short* __restrict__ Be,
    const float* __restrict__ dbk, const float* __restrict__ dbv,
    const float* __restrict__ ebk, const float* __restrict__ ebv,
    short* __restrict__ Kd, short* __restrict__ Vd,
    short* __restrict__ Ke, short* __restrict__ Ve)
{
    __shared__ short As[2][64*32];
    __shared__ short Bs[2][128*32];
    int z = blockIdx.z; int enc = z>>3; int zl = z&7;
    const short* A  = enc ? Az : Ay;
    const short* Bb = (enc ? Be : Bd) + zl*65536;
    const float* b1 = enc ? ebk : dbk;
    const float* b2 = enc ? ebv : dbv;
    short* o1 = enc ? Ke : Kd;
    short* o2 = enc ? Ve : Vd;
    int m0 = blockIdx.x*64;
    int tid = threadIdx.x, wave = tid>>6, lane = tid&63, quad = lane>>4, nl = lane&15;
    int wm = (wave&1)*32, wn = (wave>>1)*64;
    floatx4 acc[2][4];
    #pragma unroll
    for(int i=0;i<2;i++)
        #pragma unroll
        for(int j=0;j<4;j++) acc[i][j] = (floatx4){0.f,0.f,0.f,0.f};
    int r = tid>>2, c = (tid&3)*8;
    auto stage = [&](int b, int k0){
        __builtin_amdgcn_global_load_lds(
            (const __attribute__((address_space(1))) unsigned*)(A + (long)(m0 + r)*512 + k0 + c),
            (__attribute__((address_space(3))) unsigned*)((char*)As[b] + wave*1024), 16, 0, 0);
        #pragma unroll
        for(int i=0;i<2;i++)
            __builtin_amdgcn_global_load_lds(
                (const __attribute__((address_space(1))) unsigned*)(Bb + (long)(r + i*64)*512 + k0 + c),
                (__attribute__((address_space(3))) unsigned*)((char*)Bs[b] + i*4096 + wave*1024), 16, 0, 0);
    };
    stage(0, 0);
    VM0_BARRIER();
    int cur = 0;
    for(int k0=0;k0<512;k0+=32){
        if(k0 + 32 < 512) stage(cur^1, k0+32);
        short8 af[2], bfr[4];
        #pragma unroll
        for(int i=0;i<2;i++) af[i] = *(const short8*)(As[cur] + (wm + i*16 + nl)*32 + quad*8);
        #pragma unroll
        for(int j=0;j<4;j++) bfr[j] = *(const short8*)(Bs[cur] + (wn + j*16 + nl)*32 + quad*8);
        #pragma unroll
        for(int i=0;i<2;i++)
            #pragma unroll
            for(int j=0;j<4;j++)
                acc[i][j] = __builtin_amdgcn_mfma_f32_16x16x32_bf16(af[i],bfr[j],acc[i][j],0,0,0);
        VM0_BARRIER();
        cur ^= 1;
    }
    #pragma unroll
    for(int j=0;j<4;j++){
        int n = wn + j*16 + nl;
        float bv = (n >= 64) ? b2[zl*64 + n - 64] : b1[zl*64 + n];
        #pragma unroll
        for(int i=0;i<2;i++){
            #pragma unroll
            for(int rr=0;rr<4;rr++){
                int m = m0 + wm + i*16 + quad*4 + rr;
                float v = acc[i][j][rr] + bv;
                long zb = (long)(zl*NB_ + (m>>10));
                if(n >= 64) o2[ (zb*KD_ + (n-64))*S_ + (m&1023) ] = f2bf(v);
                else        o1[ (zb*S_ + (m&1023))*KD_ + n ] = f2bf(v);
            }
        }
    }
}

// ---------------- projection GEMM for Q (2-phase double-buffered) ----------------
__global__ __launch_bounds__(256) void gemm_projq_kernel(
    const short* __restrict__ A, const short* __restrict__ Bt,
    const float* __restrict__ b1, short* __restrict__ o1)
{
    __shared__ short As[2][64*32];
    __shared__ short Bs[2][64*32];
    int z = blockIdx.z;
    int m0 = blockIdx.x*64;
    const short* Bb = Bt + (long)z*(64*512);
    int tid = threadIdx.x, wave = tid>>6, lane = tid&63, quad = lane>>4, nl = lane&15;
    int wm = (wave&1)*32, wn = (wave>>1)*32;
    floatx4 acc[2][2];
    #pragma unroll
    for(int i=0;i<2;i++)
        #pragma unroll
        for(int j=0;j<2;j++) acc[i][j] = (floatx4){0.f,0.f,0.f,0.f};
    int r = tid>>2, c = (tid&3)*8;
    auto stage = [&](int b, int k0){
        __builtin_amdgcn_global_load_lds(
            (const __attribute__((address_space(1))) unsigned*)(A + (long)(m0 + r)*512 + k0 + c),
            (__attribute__((address_space(3))) unsigned*)((char*)As[b] + wave*1024), 16, 0, 0);
        __builtin_amdgcn_global_load_lds(
            (const __attribute__((address_space(1))) unsigned*)(Bb + (long)r*512 + k0 + c),
            (__attribute__((address_space(3))) unsigned*)((char*)Bs[b] + wave*1024), 16, 0, 0);
    };
    stage(0, 0);
    VM0_BARRIER();
    int cur = 0;
    for(int k0=0;k0<512;k0+=32){
        if(k0 + 32 < 512) stage(cur^1, k0+32);
        short8 af[2], bfr[2];
        #pragma unroll
        for(int i=0;i<2;i++) af[i] = *(const short8*)(As[cur] + (wm + i*16 + nl)*32 + quad*8);
        #pragma unroll
        for(int j=0;j<2;j++) bfr[j] = *(const short8*)(Bs[cur] + (wn + j*16 + nl)*32 + quad*8);
        #pragma unroll
        for(int i=0;i<2;i++)
            #pragma unroll
            for(int j=0;j<2;j++)
                acc[i][j] = __builtin_amdgcn_mfma_f32_16x16x32_bf16(af[i],bfr[j],acc[i][j],0,0,0);
        VM0_BARRIER();
        cur ^= 1;
    }
    #pragma unroll
    for(int j=0;j<2;j++){
        int n = wn + j*16 + nl;
        float bv = b1[z*64 + n];
        #pragma unroll
        for(int i=0;i<2;i++){
            #pragma unroll
            for(int rr=0;rr<4;rr++){
                int m = m0 + wm + i*16 + quad*4 + rr;
                float v = acc[i][j][rr] + bv;
                long zb = (long)(z*NB_ + (m>>10));
                o1[ (zb*S_ + (m&1023))*KD_ + n ] = f2bf(v);
            }
        }
    }
}

// ---------------- big MFMA GEMM, m97 pattern, 2-phase double-buffered ----------------
template<int TM, int TN, int OUTBF, int RELU>
__global__ __launch_bounds__(256) void gemm_big_kernel(
    const short* __restrict__ A, const short* __restrict__ Bt, const float* __restrict__ bias,
    void* __restrict__ out, int M, int N, int K)
{
    __shared__ short As[2][TM*32];
    __shared__ short Bs[2][TN*32];
    int m0 = blockIdx.x*TM, n0 = blockIdx.y*TN;
    int tid = threadIdx.x, wave = tid>>6, lane = tid&63, quad = lane>>4, nl = lane&15;
    constexpr int MI = TM/32, NI = TN/32;
    int wm = (wave&1)*(TM/2), wn = (wave>>1)*(TN/2);
    floatx4 acc[MI][NI];
    #pragma unroll
    for(int i=0;i<MI;i++)
        #pragma unroll
        for(int j=0;j<NI;j++) acc[i][j] = (floatx4){0.f,0.f,0.f,0.f};

    int r = tid>>2, c = (tid&3)*8;
    auto stage = [&](int b, int k0){
        #pragma unroll
        for(int i=0;i<TM/64;i++)
            __builtin_amdgcn_global_load_lds(
                (const __attribute__((address_space(1))) unsigned*)(A + (long)(m0 + r + i*64)*K + k0 + c),
                (__attribute__((address_space(3))) unsigned*)((char*)As[b] + i*4096 + wave*1024),
                16, 0, 0);
        #pragma unroll
        for(int i=0;i<TN/64;i++)
            __builtin_amdgcn_global_load_lds(
                (const __attribute__((address_space(1))) unsigned*)(Bt + (long)(n0 + r + i*64)*K + k0 + c),
                (__attribute__((address_space(3))) unsigned*)((char*)Bs[b] + i*4096 + wave*1024),
                16, 0, 0);
    };
    stage(0, 0);
    VM0_BARRIER();
    int cur = 0;
    for(int k0=0;k0<K;k0+=32){
        if(k0 + 32 < K) stage(cur^1, k0+32);
        short8 af[MI], bfr[NI];
        #pragma unroll
        for(int i=0;i<MI;i++) af[i] = *(const short8*)(As[cur] + (wm + i*16 + nl)*32 + quad*8);
        #pragma unroll
        for(int j=0;j<NI;j++) bfr[j] = *(const short8*)(Bs[cur] + (wn + j*16 + nl)*32 + quad*8);
        #pragma unroll
        for(int i=0;i<MI;i++)
            #pragma unroll
            for(int j=0;j<NI;j++)
                acc[i][j] = __builtin_amdgcn_mfma_f32_16x16x32_bf16(af[i],bfr[j],acc[i][j],0,0,0);
        VM0_BARRIER();
        cur ^= 1;
    }
    #pragma unroll
    for(int j=0;j<NI;j++){
        int n = n0 + wn + j*16 + nl;
        float bv = bias[n];
        #pragma unroll
        for(int i=0;i<MI;i++){
            #pragma unroll
            for(int rr=0;rr<4;rr++){
                int m = m0 + wm + i*16 + quad*4 + rr;
                float v = acc[i][j][rr] + bv;
                if(RELU) v = fmaxf(v, 0.f);
                if(OUTBF) ((short*)out)[(long)m*N + n] = f2bf(v);
                else      ((float*)out)[(long)m*N + n] = v;
            }
        }
    }
}

// ---------------- fused attention v12 (round-6 best: bracket + hybrid bisection) ----------------
__global__ __launch_bounds__(512,6) void attn_kernel(
    const short* __restrict__ Qb, const short* __restrict__ Kb, const short* __restrict__ Vt,
    const short* __restrict__ graph, short* __restrict__ ctx, int causal)
{
    __shared__ short attb[16*1024];   // 32 KiB
    __shared__ float pbuf[16*68];     // 4.25 KiB
    int hn = blockIdx.x, qt = blockIdx.y;
    int h = hn>>2, n = hn&3;
    int q0 = qt*16;
    int tid=threadIdx.x, wave=tid>>6, lane=tid&63, quad=lane>>4, nl=lane&15;

    if(causal){
        uint4v fv = (uint4v){0xff80ff80u,0xff80ff80u,0xff80ff80u,0xff80ff80u};
        #pragma unroll
        for(int i=0;i<4;i++) *(uint4v*)((char*)attb + tid*16 + i*8192) = fv;
        __syncthreads();
    }

    // ---- phase 1: scores -> bf16 LDS (rot 8q), diagonal tile masked to -inf ----
    const short* Qp = Qb + ((long)hn*S_ + q0 + nl)*KD_ + quad*8;
    short8 aq0 = *(const short8*)(Qp);
    short8 aq1 = *(const short8*)(Qp + 32);
    const short* Kp = Kb + (long)hn*S_*KD_;
    int stmax = causal ? qt : 63;
    for(int st=wave; st<=stmax; st+=8){
        const short* kp = Kp + (st*16 + nl)*KD_ + quad*8;
        short8 b0 = *(const short8*)(kp);
        short8 b1 = *(const short8*)(kp + 32);
        floatx4 cc = (floatx4){0.f,0.f,0.f,0.f};
        cc = __builtin_amdgcn_mfma_f32_16x16x32_bf16(aq0,b0,cc,0,0,0);
        cc = __builtin_amdgcn_mfma_f32_16x16x32_bf16(aq1,b1,cc,0,0,0);
        int s = st*16 + nl;
        #pragma unroll
        for(int rr=0;rr<4;rr++){
            int q = quad*4 + rr;
            short val = f2bf(cc[rr]*0.125f);
            if(causal && s > q0 + q) val = (short)0xff80;   // -inf
            attb[q*1024 + ((s + 8*q)&1023)] = val;
        }
    }
    __syncthreads();

    // ---- phase 2: top-128 + softmax + graph blend; 2 sequential rows/wave ----
    #pragma unroll 1
    for(int rp=0; rp<2; ++rp){
        int q = wave*2 + rp;
        int qg = q0 + q;
        short* rowp = attb + q*1024;
        int sb = lane*16;
        int p0 = (sb + 8*q) & 1023;
        const short* grow = graph + (long)qg*1024 + sb;
        uint4v g0 = *(const uint4v*)(grow);
        uint4v g1 = *(const uint4v*)(grow + 8);
        uint4v u0 = *(const uint4v*)(rowp + p0);
        uint4v u1 = *(const uint4v*)(rowp + ((p0+8)&1023));
        unsigned pr[8];
        #pragma unroll
        for(int i=0;i<4;i++){ pr[i] = u0[i]; pr[4+i] = u1[i]; }
        unsigned kv[16];
        #pragma unroll
        for(int i=0;i<8;i++){
            unsigned u = pr[i];
            unsigned kp = u ^ (0x80008000u + ((u>>15)&0x00010001u)*0x7fffu);
            kv[2*i]   = kp & 0xffffu;
            kv[2*i+1] = kp >> 16;
        }
        unsigned a0 = umaxu(kv[0],kv[1]),  a1 = umaxu(kv[2],kv[3]);
        unsigned a2 = umaxu(kv[4],kv[5]),  a3 = umaxu(kv[6],kv[7]);
        unsigned a4 = umaxu(kv[8],kv[9]),  a5 = umaxu(kv[10],kv[11]);
        unsigned a6 = umaxu(kv[12],kv[13]),a7 = umaxu(kv[14],kv[15]);
        unsigned mk = umaxu(umaxu(umaxu(a0,a1),umaxu(a2,a3)), umaxu(umaxu(a4,a5),umaxu(a6,a7)));
        unsigned mks = wmax_dpp_u(mk);
        unsigned lmin = wmin_dpp_u(mk);
        // bracket-establishing probe at lmin
        unsigned lo, hi;
        {
            unsigned cnt = count128(kv, lmin);
            if(cnt >= 128u){ lo = lmin; hi = (cnt == 128u) ? (lmin + 1u) : (mks + 1u); }
            else           { lo = 0u;   hi = lmin; }
        }
        // bisection: largest m with count(key >= m) >= 128
        while(hi - lo > 1u){
            unsigned mid = (lo + hi) >> 1;
            unsigned cnt = count128(kv, mid);
            if(cnt >= 128u){ lo = mid; if(cnt == 128u) break; }
            else hi = mid;
        }
        // row max as float (uniform)
        unsigned uo = (mks & 0x8000u) ? ((mks & 0x7fffu)<<16) : ((~mks)<<16);
        float mxf = __builtin_bit_cast(float, uo);
        float ev[16]; float sm = 0.f;
        #pragma unroll
        for(int i=0;i<8;i++){
            float f0 = __builtin_bit_cast(float, pr[i] << 16);
            float f1 = __builtin_bit_cast(float, pr[i] & 0xffff0000u);
            float e0 = __expf(f0 - mxf);
            float e1 = __expf(f1 - mxf);
            e0 = (kv[2*i]   >= lo) ? e0 : 0.f;
            e1 = (kv[2*i+1] >= lo) ? e1 : 0.f;
            ev[2*i] = e0; ev[2*i+1] = e1;
            sm += e0 + e1;
        }
        sm = wsum_dpp_f(sm);
        float inv = 0.5f / sm;   // (1-gw) = 0.5; graph holds 0.5*softmax
        uint4v w0, w1;
        #pragma unroll
        for(int i=0;i<4;i++){
            float gl0 = __builtin_bit_cast(float, g0[i] << 16);
            float gh0 = __builtin_bit_cast(float, g0[i] & 0xffff0000u);
            w0[i] = cvt_pk_bf16(fmaf(ev[2*i], inv, gl0), fmaf(ev[2*i+1], inv, gh0));
            float gl1 = __builtin_bit_cast(float, g1[i] << 16);
            float gh1 = __builtin_bit_cast(float, g1[i] & 0xffff0000u);
            w1[i] = cvt_pk_bf16(fmaf(ev[8+2*i], inv, gl1), fmaf(ev[8+2*i+1], inv, gh1));
        }
        *(uint4v*)(rowp + p0) = w0;
        *(uint4v*)(rowp + ((p0+8)&1023)) = w1;
    }
    __syncthreads();

    // ---- phase 3: ctx = att @ V, split over s-halves (sh), v-quarters (vh) ----
    int vh = wave & 3, sh = wave >> 2;
    int v0 = vh*16;
    const short* Vp = Vt + ((long)hn*KD_ + v0 + nl)*S_;
    floatx4 o4 = (floatx4){0.f,0.f,0.f,0.f};
    int arow = nl;
    int sbase = sh*512;
    for(int s0=sbase; s0<sbase+512; s0+=32){
        int cs = (s0 + quad*8 + 8*arow) & 1023;
        short8 ap = *(const short8*)(attb + arow*1024 + cs);
        short8 bv = *(const short8*)(Vp + s0 + quad*8);
        o4 = __builtin_amdgcn_mfma_f32_16x16x32_bf16(ap,bv,o4,0,0,0);
    }
    if(sh==1){
        #pragma unroll
        for(int rr=0;rr<4;rr++) pbuf[(quad*4+rr)*68 + v0 + nl] = o4[rr];
    }
    __syncthreads();
    if(sh==0){
        #pragma unroll
        for(int rr=0;rr<4;rr++){
            int q = quad*4 + rr;
            float v = o4[rr] + pbuf[q*68 + v0 + nl];
            ctx[ ((long)(n*S_ + q0 + q))*512 + h*KD_ + v0 + nl ] = f2bf(v);
        }
    }
}

// ---------------- LayerNorm(x + res) ----------------
__global__ __launch_bounds__(256) void ln_kernel(const float* __restrict__ x, const float* __restrict__ res,
                                                 float* __restrict__ outf, short* __restrict__ outb){
    long row = blockIdx.x;
    const float* xr = x + row*D_;
    const float* rr = res + row*D_;
    int tid = threadIdx.x, wave = tid>>6, lane = tid&63;
    float t0 = xr[tid] + rr[tid];
    float t1 = xr[tid+256] + rr[tid+256];
    float s = t0 + t1, s2 = t0*t0 + t1*t1;
    __shared__ float red[8];
    s = wred_addf(s); s2 = wred_addf(s2);
    if(lane==0){ red[wave] = s; red[4+wave] = s2; }
    __syncthreads();
    s  = red[0]+red[1]+red[2]+red[3];
    s2 = red[4]+red[5]+red[6]+red[7];
    float mean = s*(1.f/512.f);
    float var = s2*(1.f/512.f) - mean*mean;
    float rs = rsqrtf(var + 1e-5f);
    float o0 = (t0-mean)*rs, o1 = (t1-mean)*rs;
    if(outf){ outf[row*D_+tid] = o0; outf[row*D_+tid+256] = o1; }
    if(outb){ outb[row*D_+tid] = f2bf(o0); outb[row*D_+tid+256] = f2bf(o1); }
}

extern "C" void kernel_launch(void* const* d_in, const int* in_sizes, int n_in,
                              void* d_out, int out_size, void* d_ws, size_t ws_size,
                              hipStream_t stream)
{
    const float* z         = (const float*)d_in[0];
    const float* y         = (const float*)d_in[1];
    const float* graph_dec = (const float*)d_in[2];
    const float* graph_enc = (const float*)d_in[3];
    const float* dec_Wk = (const float*)d_in[4];  const float* dec_bk = (const float*)d_in[5];
    const float* dec_Wv = (const float*)d_in[6];  const float* dec_bv = (const float*)d_in[7];
    const float* dec_Wo = (const float*)d_in[8];  const float* dec_bo = (const float*)d_in[9];
    const float* enc_Wk = (const float*)d_in[10]; const float* enc_bk = (const float*)d_in[11];
    const float* enc_Wq = (const float*)d_in[12]; const float* enc_bq = (const float*)d_in[13];
    const float* enc_Wv = (const float*)d_in[14]; const float* enc_bv = (const float*)d_in[15];
    const float* enc_Wo = (const float*)d_in[16]; const float* enc_bo = (const float*)d_in[17];
    const float* fc_W1  = (const float*)d_in[18]; const float* fc_b1  = (const float*)d_in[19];
    const float* fc_W2  = (const float*)d_in[20]; const float* fc_b2  = (const float*)d_in[21];

    char* ws = (char*)d_ws;
    short* gdec  = (short*)(ws + 0x0000000);
    short* genc  = (short*)(ws + 0x0400000);
    short* y_bf  = (short*)(ws + 0x0800000);
    short* z_bf  = (short*)(ws + 0x0C00000);
    short* Kdec  = (short*)(ws + 0x1000000);
    short* Vtdec = (short*)(ws + 0x1400000);
    short* Kenc  = (short*)(ws + 0x1800000);
    short* Vtenc = (short*)(ws + 0x1C00000);
    short* Qenc  = (short*)(ws + 0x2000000);
    short* ctx   = (short*)(ws + 0x2400000);
    float* tmp   = (float*)(ws + 0x2800000);
    float* hbuf  = (float*)(ws + 0x3000000);
    short* h_bf  = (short*)(ws + 0x3800000);
    float* h2    = (float*)(ws + 0x3C00000);
    short* h2_bf = (short*)(ws + 0x4400000);
    short* fc1   = (short*)(ws + 0x4800000);
    short* wKVd  = (short*)(ws + 0x5800000);
    short* wKVe  = (short*)(ws + 0x5900000);
    short* wQet  = (short*)(ws + 0x5A00000);
    short* wOdt  = (short*)(ws + 0x5A80000);
    short* wOet  = (short*)(ws + 0x5B00000);
    short* wF1t  = (short*)(ws + 0x5B80000);
    short* wF2t  = (short*)(ws + 0x5D80000);
    float* outp  = (float*)d_out;

    dim3 B(256);
    // 1) all preprocessing in one dispatch
    prep_kernel<<<dim3(9984),B,0,stream>>>(
        dec_Wk, dec_Wv, enc_Wk, enc_Wv, enc_Wq, dec_Wo, enc_Wo, fc_W1, fc_W2,
        y, z, graph_dec, graph_enc,
        wKVd, wKVe, wQet, wOdt, wOet, wF1t, wF2t, y_bf, z_bf, gdec, genc);
    // 2) dec + enc KV projections in one dispatch
    gemm_projkv_kernel<<<dim3(64,1,16),B,0,stream>>>(
        y_bf, z_bf, wKVd, wKVe, dec_bk, dec_bv, enc_bk, enc_bv,
        Kdec, Vtdec, Kenc, Vtenc);
    // 3) decoder stage — Wo GEMM at 64x64 tiles (grid 512 = 2 blocks/CU)
    attn_kernel<<<dim3(32,64),dim3(512),0,stream>>>(Kdec, Kdec, Vtdec, gdec, ctx, 1);
    gemm_big_kernel<64,64,0,0><<<dim3(64,8),B,0,stream>>>(ctx, wOdt, dec_bo, tmp, 4096, 512, 512);
    ln_kernel<<<dim3(4096),B,0,stream>>>(tmp, y, hbuf, h_bf);
    // 4) encoder-decoder stage
    gemm_projq_kernel<<<dim3(64,1,8),B,0,stream>>>(h_bf, wQet, enc_bq, Qenc);
    attn_kernel<<<dim3(32,64),dim3(512),0,stream>>>(Qenc, Kenc, Vtenc, genc, ctx, 0);
    gemm_big_kernel<64,64,0,0><<<dim3(64,8),B,0,stream>>>(ctx, wOet, enc_bo, tmp, 4096, 512, 512);
    ln_kernel<<<dim3(4096),B,0,stream>>>(tmp, hbuf, h2, h2_bf);
    // 5) MLP — MLP2 at 64x64 tiles (grid 512 = 2 blocks/CU)
    gemm_big_kernel<128,128,1,1><<<dim3(32,16),B,0,stream>>>(h2_bf, wF1t, fc_b1, fc1, 4096, 2048, 512);
    gemm_big_kernel<64,64,0,0><<<dim3(64,8),B,0,stream>>>(fc1, wF2t, fc_b2, tmp, 4096, 512, 2048);
    ln_kernel<<<dim3(4096),B,0,stream>>>(tmp, h2, outp, (short*)0);
}